// Round 3
// baseline (1004.177 us; speedup 1.0000x reference)
//
#include <hip/hip_runtime.h>
#include <hip/hip_bf16.h>

// Problem constants
// x: (4,1,16,64,64) int32, tokens in [0,256), PAD=-1
// conv_w: (512, 256, 2,4,4), stride==kernel -> gather of 32 taps
// grid after conv: (4, 512, 8, 16, 16); attention blocks (4,8,8) -> 32 blocks x 256 tokens
#define DEC 512
#define NTAP 32
#define NROWS 8192   // 4 * 8*16*16 positions, stored attention-block-major
#define LTOK 256
#define HD 64

// ---------------- transpose conv_w (512 x 8192) -> wT (8192 x 512) ----------------
__global__ void k_transpose(const float* __restrict__ src, float* __restrict__ dst) {
  __shared__ float tile[32][65];
  int vt0 = blockIdx.x * 64;   // v*32+tap index
  int de0 = blockIdx.y * 32;   // output channel
  int tid = threadIdx.x;       // 256
  int vtl = tid & 63, del = tid >> 6;
#pragma unroll
  for (int p = 0; p < 8; p++) {
    tile[del + 4 * p][vtl] = src[(size_t)(de0 + del + 4 * p) * 8192 + vt0 + vtl];
  }
  __syncthreads();
  int del2 = tid & 31, vtl2 = tid >> 5;
#pragma unroll
  for (int p = 0; p < 8; p++) {
    dst[(size_t)(vt0 + vtl2 + 8 * p) * 512 + de0 + del2] = tile[del2][vtl2 + 8 * p];
  }
}

// ---------------- embed: gather conv rows + bias + slice emb ----------------
// writes H0 rows in attention-block-major order:
// r = (((b*2+bt)*2+bh)*2+bw)*256 + ((lt*8+lh)*8+lw)
__global__ void k_embed(const int* __restrict__ x, const int* __restrict__ slice_idx,
                        const float* __restrict__ wT, const float* __restrict__ conv_b,
                        const float* __restrict__ slice_emb, float* __restrict__ H0) {
  int r = blockIdx.x;        // 0..8191
  int tid = threadIdx.x;     // 256
  int blk = r >> 8, l = r & 255;
  int bw = blk & 1, bh = (blk >> 1) & 1, bt = (blk >> 2) & 1, b = blk >> 3;
  int lw = l & 7, lh = (l >> 3) & 7, lt = l >> 6;
  int t = bt * 4 + lt, h = bh * 8 + lh, w = bw * 8 + lw;

  __shared__ int toks[NTAP];
  if (tid < NTAP) {
    int kt = tid >> 4, kh = (tid >> 2) & 3, kw = tid & 3;
    toks[tid] = x[((b * 16 + (2 * t + kt)) * 64 + (4 * h + kh)) * 64 + (4 * w + kw)];
  }
  __syncthreads();
  int sl = slice_idx[b];
  float acc0 = conv_b[tid] + slice_emb[sl * 512 + tid];
  float acc1 = conv_b[tid + 256] + slice_emb[sl * 512 + tid + 256];
  for (int tap = 0; tap < NTAP; tap++) {
    int v = toks[tap];
    if (v >= 0) {
      const float* wrow = wT + (size_t)(v * NTAP + tap) * 512;
      acc0 += wrow[tid];
      acc1 += wrow[tid + 256];
    }
  }
  H0[(size_t)r * 512 + tid] = acc0;
  H0[(size_t)r * 512 + tid + 256] = acc1;
}

// ---------------- fp32 GEMM: C(M,512) = A(M,512) @ B(512,512) [+C] ----------------
// BT=true: B[k][n] = Bsrc[n*512+k] (i.e. Bsrc is (N,K) row-major)
template <bool BT, bool RES>
__global__ void k_gemm(const float* __restrict__ A, const float* __restrict__ B,
                       float* __restrict__ C) {
  __shared__ float As[16][68];
  __shared__ float Bs[16][68];
  int m0 = blockIdx.x * 64, n0 = blockIdx.y * 64;
  int tid = threadIdx.x;           // 256
  int tx = tid & 15, ty = tid >> 4;
  float c[4][4] = {};
  for (int k0 = 0; k0 < 512; k0 += 16) {
#pragma unroll
    for (int p = 0; p < 4; p++) {
      int row = ty + 16 * p;
      As[tx][row] = A[(size_t)(m0 + row) * 512 + k0 + tx];
    }
    if (BT) {
#pragma unroll
      for (int p = 0; p < 4; p++) {
        int col = ty + 16 * p;
        Bs[tx][col] = B[(size_t)(n0 + col) * 512 + k0 + tx];
      }
    } else {
      int col = tid & 63, kk = tid >> 6;
#pragma unroll
      for (int p = 0; p < 4; p++) {
        Bs[kk + 4 * p][col] = B[(size_t)(k0 + kk + 4 * p) * 512 + n0 + col];
      }
    }
    __syncthreads();
#pragma unroll
    for (int k = 0; k < 16; k++) {
      float a[4], bb[4];
#pragma unroll
      for (int i = 0; i < 4; i++) a[i] = As[k][ty * 4 + i];
#pragma unroll
      for (int j = 0; j < 4; j++) bb[j] = Bs[k][tx * 4 + j];
#pragma unroll
      for (int i = 0; i < 4; i++)
#pragma unroll
        for (int j = 0; j < 4; j++) c[i][j] += a[i] * bb[j];
    }
    __syncthreads();
  }
#pragma unroll
  for (int i = 0; i < 4; i++) {
    float4* cp = (float4*)&C[(size_t)(m0 + ty * 4 + i) * 512 + n0 + tx * 4];
    float4 v = make_float4(c[i][0], c[i][1], c[i][2], c[i][3]);
    if (RES) {
      float4 r = *cp;
      v.x += r.x; v.y += r.y; v.z += r.z; v.w += r.w;
    }
    *cp = v;
  }
}

// ---------------- block-local attention: one WG per (block, head) ----------------
__global__ void __launch_bounds__(256, 1)
k_attn(const float* __restrict__ Q, const float* __restrict__ K,
       const float* __restrict__ V, float* __restrict__ O) {
  __shared__ float Ks[LTOK * HD];  // 64 KiB
  __shared__ float Vs[LTOK * HD];  // 64 KiB
  int bid = blockIdx.x >> 3, head = blockIdx.x & 7;
  int r0 = bid * LTOK;
  int tid = threadIdx.x;           // 256 = one thread per query row
  for (int idx = tid; idx < LTOK * HD; idx += 256) {
    int l = idx >> 6, i = idx & 63;
    Ks[idx] = K[(size_t)(r0 + l) * 512 + head * 64 + i];
    Vs[idx] = V[(size_t)(r0 + l) * 512 + head * 64 + i];
  }
  __syncthreads();
  float q[64];
  const float4* qp = (const float4*)&Q[(size_t)(r0 + tid) * 512 + head * 64];
#pragma unroll
  for (int i = 0; i < 16; i++) {
    float4 t = qp[i];
    q[4 * i] = t.x; q[4 * i + 1] = t.y; q[4 * i + 2] = t.z; q[4 * i + 3] = t.w;
  }
  float o[64];
#pragma unroll
  for (int i = 0; i < 64; i++) o[i] = 0.f;
  float m = -1e30f, lsum = 0.f;
  const float4* Ks4 = (const float4*)Ks;
  const float4* Vs4 = (const float4*)Vs;
  for (int k = 0; k < LTOK; k++) {
    float s = 0.f;
#pragma unroll
    for (int i = 0; i < 16; i++) {
      float4 kv = Ks4[k * 16 + i];
      s += q[4 * i] * kv.x + q[4 * i + 1] * kv.y + q[4 * i + 2] * kv.z + q[4 * i + 3] * kv.w;
    }
    s *= 0.125f;  // 1/sqrt(64)
    float mn = fmaxf(m, s);
    float p = __expf(s - mn);
    float cfac = __expf(m - mn);
    lsum = lsum * cfac + p;
#pragma unroll
    for (int i = 0; i < 16; i++) {
      float4 vv = Vs4[k * 16 + i];
      o[4 * i]     = o[4 * i]     * cfac + p * vv.x;
      o[4 * i + 1] = o[4 * i + 1] * cfac + p * vv.y;
      o[4 * i + 2] = o[4 * i + 2] * cfac + p * vv.z;
      o[4 * i + 3] = o[4 * i + 3] * cfac + p * vv.w;
    }
    m = mn;
  }
  float inv = 1.f / lsum;
  float4* op = (float4*)&O[(size_t)(r0 + tid) * 512 + head * 64];
#pragma unroll
  for (int i = 0; i < 16; i++) {
    op[i] = make_float4(o[4 * i] * inv, o[4 * i + 1] * inv, o[4 * i + 2] * inv, o[4 * i + 3] * inv);
  }
}

// ---------------- writeout: block-major rows -> (b, d, t, h, w) FLOAT32 ----------------
// Reference output dtype is float32 (out_npz ~15.5MB = 4.19M f32), NOT bf16.
__global__ void k_writeout(const float* __restrict__ H, float* __restrict__ out) {
  int idx = blockIdx.x * 256 + threadIdx.x;  // 4*512*8*16*16 = 4194304
  int w = idx & 15, h = (idx >> 4) & 15, t = (idx >> 8) & 7;
  int d = (idx >> 11) & 511, b = idx >> 20;
  int r = (((b * 2 + (t >> 2)) * 2 + (h >> 3)) * 2 + (w >> 3)) * 256 +
          (((t & 3) * 8 + (h & 7)) * 8 + (w & 7));
  out[idx] = H[(size_t)r * 512 + d];
}

extern "C" void kernel_launch(void* const* d_in, const int* in_sizes, int n_in,
                              void* d_out, int out_size, void* d_ws, size_t ws_size,
                              hipStream_t stream) {
  const int* x = (const int*)d_in[0];
  const int* slice_idx = (const int*)d_in[1];
  const float* conv_w = (const float*)d_in[2];
  const float* conv_b = (const float*)d_in[3];
  const float* slice_emb = (const float*)d_in[4];
  const float* proj_w = (const float*)d_in[5];
  const float* wq = (const float*)d_in[6];
  const float* wk = (const float*)d_in[7];
  const float* wv = (const float*)d_in[8];
  const float* wo = (const float*)d_in[9];
  float* out = (float*)d_out;

  float* ws = (float*)d_ws;
  const size_t SZ = (size_t)NROWS * 512;  // 4,194,304 floats
  float* wT = ws;            // 8192*512 floats; dead after k_embed -> aliased by Ob
  float* Ob = ws;
  float* Qb = ws + SZ;       // also used as H0
  float* Kb = Qb + SZ;
  float* Vb = Kb + SZ;
  float* H  = Vb + SZ;       // total 5 * 16 MiB = 80 MiB

  k_transpose<<<dim3(128, 16), 256, 0, stream>>>(conv_w, wT);
  k_embed<<<NROWS, 256, 0, stream>>>(x, slice_idx, wT, conv_b, slice_emb, Qb);
  k_gemm<true, false><<<dim3(128, 8), 256, 0, stream>>>(Qb, proj_w, H);

  for (int L = 0; L < 2; L++) {
    const float* wql = wq + (size_t)L * 512 * 512;
    const float* wkl = wk + (size_t)L * 512 * 512;
    const float* wvl = wv + (size_t)L * 512 * 512;
    const float* wol = wo + (size_t)L * 512 * 512;
    k_gemm<false, false><<<dim3(128, 8), 256, 0, stream>>>(H, wql, Qb);
    k_gemm<false, false><<<dim3(128, 8), 256, 0, stream>>>(H, wkl, Kb);
    k_gemm<false, false><<<dim3(128, 8), 256, 0, stream>>>(H, wvl, Vb);
    k_attn<<<256, 256, 0, stream>>>(Qb, Kb, Vb, Ob);
    k_gemm<false, true><<<dim3(128, 8), 256, 0, stream>>>(Ob, wol, H);
  }
  k_writeout<<<16384, 256, 0, stream>>>(H, out);
}

// Round 5
// 582.486 us; speedup vs baseline: 1.7240x; 1.7240x over previous
//
#include <hip/hip_runtime.h>
#include <hip/hip_bf16.h>

typedef unsigned short u16x8 __attribute__((ext_vector_type(8)));
typedef __bf16 bf16x8 __attribute__((ext_vector_type(8)));
typedef float f32x4 __attribute__((ext_vector_type(4)));

#define NTAP 32
#define NROWS 8192
#define LTOK 256

__device__ inline unsigned short bf16bits(float f) {
  __hip_bfloat16 hb = __float2bfloat16(f);
  return __builtin_bit_cast(unsigned short, hb);
}

// ---------------- transpose conv_w (512 x 8192) -> wT (8192 x 512) fp32 ----------------
__global__ void k_transpose(const float* __restrict__ src, float* __restrict__ dst) {
  __shared__ float tile[32][65];
  int vt0 = blockIdx.x * 64;
  int de0 = blockIdx.y * 32;
  int tid = threadIdx.x;
  int vtl = tid & 63, del = tid >> 6;
#pragma unroll
  for (int p = 0; p < 8; p++)
    tile[del + 4 * p][vtl] = src[(size_t)(de0 + del + 4 * p) * 8192 + vt0 + vtl];
  __syncthreads();
  int del2 = tid & 31, vtl2 = tid >> 5;
#pragma unroll
  for (int p = 0; p < 8; p++)
    dst[(size_t)(vt0 + vtl2 + 8 * p) * 512 + de0 + del2] = tile[del2][vtl2 + 8 * p];
}

// ---------------- weights -> bf16, layout Wb[mat][n][k] (n-major, k contiguous) ----------
// mat 0: proj (dst[n][k] = proj_w[n][k], direct). mat 1..8: attn weights, transposed:
// dst[n][k] = w[k][n].  offsets: mat*262144.
__global__ void k_prepw(const float* __restrict__ proj_w, const float* __restrict__ wq,
                        const float* __restrict__ wk, const float* __restrict__ wv,
                        const float* __restrict__ wo, unsigned short* __restrict__ Wb) {
  __shared__ float tile[64][65];
  int mat = blockIdx.z;
  int n0 = blockIdx.x * 64, k0 = blockIdx.y * 64;
  int t = threadIdx.x;
  unsigned short* dst = Wb + (size_t)mat * 262144;
  if (mat == 0) {
#pragma unroll
    for (int p = 0; p < 16; p++) {
      int r = p * 4 + (t >> 6), c = t & 63;
      dst[(size_t)(n0 + r) * 512 + k0 + c] = bf16bits(proj_w[(size_t)(n0 + r) * 512 + k0 + c]);
    }
  } else {
    int idx = mat - 1, comp = idx & 3, L = idx >> 2;
    const float* srcs[4] = {wq, wk, wv, wo};
    const float* src = srcs[comp] + (size_t)L * 262144;
#pragma unroll
    for (int p = 0; p < 16; p++) {
      int r = p * 4 + (t >> 6), c = t & 63;
      tile[r][c] = src[(size_t)(k0 + r) * 512 + n0 + c];
    }
    __syncthreads();
#pragma unroll
    for (int p = 0; p < 16; p++) {
      int r = p * 4 + (t >> 6), c = t & 63;
      dst[(size_t)(n0 + r) * 512 + k0 + c] = bf16bits(tile[c][r]);
    }
  }
}

// ---------------- embed: gather conv rows + bias + slice emb -> bf16 rows ----------------
__global__ void k_embed(const int* __restrict__ x, const int* __restrict__ slice_idx,
                        const float* __restrict__ wT, const float* __restrict__ conv_b,
                        const float* __restrict__ slice_emb, unsigned short* __restrict__ H0b) {
  int r = blockIdx.x;
  int tid = threadIdx.x;
  int blk = r >> 8, l = r & 255;
  int bw = blk & 1, bh = (blk >> 1) & 1, bt = (blk >> 2) & 1, b = blk >> 3;
  int lw = l & 7, lh = (l >> 3) & 7, lt = l >> 6;
  int t = bt * 4 + lt, h = bh * 8 + lh, w = bw * 8 + lw;

  __shared__ int toks[NTAP];
  if (tid < NTAP) {
    int kt = tid >> 4, kh = (tid >> 2) & 3, kw = tid & 3;
    toks[tid] = x[((b * 16 + (2 * t + kt)) * 64 + (4 * h + kh)) * 64 + (4 * w + kw)];
  }
  __syncthreads();
  int sl = slice_idx[b];
  float acc0 = conv_b[tid] + slice_emb[sl * 512 + tid];
  float acc1 = conv_b[tid + 256] + slice_emb[sl * 512 + tid + 256];
  for (int tap = 0; tap < NTAP; tap++) {
    int v = toks[tap];
    if (v >= 0) {
      const float* wrow = wT + (size_t)(v * NTAP + tap) * 512;
      acc0 += wrow[tid];
      acc1 += wrow[tid + 256];
    }
  }
  H0b[(size_t)r * 512 + tid] = bf16bits(acc0);
  H0b[(size_t)r * 512 + tid + 256] = bf16bits(acc1);
}

// ---------------- bf16 MFMA GEMM: C(M,LDN) = A(M,512) @ B; B in [n][k] bf16 layout ------
// 128x128 tile, BK=64, 4 waves 2x2. XOR-swizzled LDS (x = slot ^ (row&7)).
template <int LDC, bool RES, bool WB16>
__global__ void __launch_bounds__(256)
k_gemm_mfma(const unsigned short* __restrict__ A, const unsigned short* __restrict__ B,
            float* __restrict__ Cf, unsigned short* __restrict__ Cb) {
  __shared__ __align__(16) unsigned short As[128 * 64];
  __shared__ __align__(16) unsigned short Bs[128 * 64];
  int m0 = blockIdx.x * 128, n0 = blockIdx.y * 128;
  int tid = threadIdx.x;
  int lane = tid & 63, wid = tid >> 6;
  int wr = wid >> 1, wc = wid & 1;
  int l15 = lane & 15, lgrp = lane >> 4;
  int srow = tid >> 3, sx = tid & 7;
  f32x4 acc[4][4] = {};
  for (int k0 = 0; k0 < 512; k0 += 64) {
    u16x8 ra[4], rb[4];
#pragma unroll
    for (int i = 0; i < 4; i++) {
      int row = i * 32 + srow;
      int c = sx ^ (row & 7);
      ra[i] = *(const u16x8*)&A[(size_t)(m0 + row) * 512 + k0 + c * 8];
      rb[i] = *(const u16x8*)&B[(size_t)(n0 + row) * 512 + k0 + c * 8];
    }
    __syncthreads();
#pragma unroll
    for (int i = 0; i < 4; i++) {
      int row = i * 32 + srow;
      *(u16x8*)&As[row * 64 + sx * 8] = ra[i];
      *(u16x8*)&Bs[row * 64 + sx * 8] = rb[i];
    }
    __syncthreads();
#pragma unroll
    for (int kk = 0; kk < 2; kk++) {
      bf16x8 a[4], b[4];
#pragma unroll
      for (int m = 0; m < 4; m++) {
        int row = wr * 64 + m * 16 + l15;
        int xx = (kk * 4 + lgrp) ^ (row & 7);
        a[m] = __builtin_bit_cast(bf16x8, *(const u16x8*)&As[row * 64 + xx * 8]);
      }
#pragma unroll
      for (int n = 0; n < 4; n++) {
        int row = wc * 64 + n * 16 + l15;
        int xx = (kk * 4 + lgrp) ^ (row & 7);
        b[n] = __builtin_bit_cast(bf16x8, *(const u16x8*)&Bs[row * 64 + xx * 8]);
      }
#pragma unroll
      for (int m = 0; m < 4; m++)
#pragma unroll
        for (int n = 0; n < 4; n++)
          acc[m][n] = __builtin_amdgcn_mfma_f32_16x16x32_bf16(a[m], b[n], acc[m][n], 0, 0, 0);
    }
  }
#pragma unroll
  for (int m = 0; m < 4; m++) {
#pragma unroll
    for (int n = 0; n < 4; n++) {
      int gcol = n0 + wc * 64 + n * 16 + l15;
#pragma unroll
      for (int r = 0; r < 4; r++) {
        int grow = m0 + wr * 64 + m * 16 + lgrp * 4 + r;
        float v = acc[m][n][r];
        if (RES) v += Cf[(size_t)grow * LDC + gcol];
        Cf[(size_t)grow * LDC + gcol] = v;
        if (WB16) Cb[(size_t)grow * 512 + gcol] = bf16bits(v);
      }
    }
  }
}

// ---------------- block-local attention (fp32), QKV fused row-stride 1536 ----------------
__global__ void __launch_bounds__(256, 1)
k_attn(const float* __restrict__ QKV, unsigned short* __restrict__ O16) {
  __shared__ float Ks[LTOK * 64];
  __shared__ float Vs[LTOK * 64];
  int bid = blockIdx.x >> 3, head = blockIdx.x & 7;
  int r0 = bid * LTOK;
  int tid = threadIdx.x;
  for (int idx = tid; idx < LTOK * 64; idx += 256) {
    int l = idx >> 6, i = idx & 63;
    Ks[idx] = QKV[(size_t)(r0 + l) * 1536 + 512 + head * 64 + i];
    Vs[idx] = QKV[(size_t)(r0 + l) * 1536 + 1024 + head * 64 + i];
  }
  __syncthreads();
  float q[64];
  const float4* qp = (const float4*)&QKV[(size_t)(r0 + tid) * 1536 + head * 64];
#pragma unroll
  for (int i = 0; i < 16; i++) {
    float4 t = qp[i];
    q[4 * i] = t.x; q[4 * i + 1] = t.y; q[4 * i + 2] = t.z; q[4 * i + 3] = t.w;
  }
  float o[64];
#pragma unroll
  for (int i = 0; i < 64; i++) o[i] = 0.f;
  float m = -1e30f, lsum = 0.f;
  const float4* Ks4 = (const float4*)Ks;
  const float4* Vs4 = (const float4*)Vs;
  for (int k = 0; k < LTOK; k++) {
    float s = 0.f;
#pragma unroll
    for (int i = 0; i < 16; i++) {
      float4 kv = Ks4[k * 16 + i];
      s += q[4 * i] * kv.x + q[4 * i + 1] * kv.y + q[4 * i + 2] * kv.z + q[4 * i + 3] * kv.w;
    }
    s *= 0.125f;
    float mn = fmaxf(m, s);
    float p = __expf(s - mn);
    float cfac = __expf(m - mn);
    lsum = lsum * cfac + p;
#pragma unroll
    for (int i = 0; i < 16; i++) {
      float4 vv = Vs4[k * 16 + i];
      o[4 * i]     = o[4 * i]     * cfac + p * vv.x;
      o[4 * i + 1] = o[4 * i + 1] * cfac + p * vv.y;
      o[4 * i + 2] = o[4 * i + 2] * cfac + p * vv.z;
      o[4 * i + 3] = o[4 * i + 3] * cfac + p * vv.w;
    }
    m = mn;
  }
  float inv = 1.f / lsum;
#pragma unroll
  for (int g = 0; g < 8; g++) {
    u16x8 pk;
#pragma unroll
    for (int j = 0; j < 8; j++) pk[j] = bf16bits(o[g * 8 + j] * inv);
    *(u16x8*)&O16[(size_t)(r0 + tid) * 512 + head * 64 + g * 8] = pk;
  }
}

// ---------------- writeout: block-major rows -> (b, d, t, h, w) f32 ----------------
__global__ void k_writeout(const float* __restrict__ H, float* __restrict__ out) {
  int idx = blockIdx.x * 256 + threadIdx.x;
  int w = idx & 15, h = (idx >> 4) & 15, t = (idx >> 8) & 7;
  int d = (idx >> 11) & 511, b = idx >> 20;
  int r = (((b * 2 + (t >> 2)) * 2 + (h >> 3)) * 2 + (w >> 3)) * 256 +
          (((t & 3) * 8 + (h & 7)) * 8 + (w & 7));
  out[idx] = H[(size_t)r * 512 + d];
}

extern "C" void kernel_launch(void* const* d_in, const int* in_sizes, int n_in,
                              void* d_out, int out_size, void* d_ws, size_t ws_size,
                              hipStream_t stream) {
  const int* x = (const int*)d_in[0];
  const int* slice_idx = (const int*)d_in[1];
  const float* conv_w = (const float*)d_in[2];
  const float* conv_b = (const float*)d_in[3];
  const float* slice_emb = (const float*)d_in[4];
  const float* proj_w = (const float*)d_in[5];
  const float* wq = (const float*)d_in[6];
  const float* wk = (const float*)d_in[7];
  const float* wv = (const float*)d_in[8];
  const float* wo = (const float*)d_in[9];
  float* out = (float*)d_out;

  float* ws = (float*)d_ws;
  // layout (f32 words): wT [0,4M) dead after embed; QKV [0,12.58M);
  // H0b bf16 @ [4M,6M) dead after proj; H @12.58M; Hb/Ob16/Wb bf16 after.
  float* wT = ws;
  unsigned short* H0b = (unsigned short*)(ws + 4194304);
  float* QKV = ws;                          // 8192 x 1536 f32
  float* H = ws + 12582912;                 // 8192 x 512 f32 (residual trunk)
  unsigned short* Hb = (unsigned short*)(ws + 16777216);    // 8192x512 bf16
  unsigned short* Ob16 = (unsigned short*)(ws + 18874368);  // 8192x512 bf16
  unsigned short* Wb = (unsigned short*)(ws + 20971520);    // 9 x 512x512 bf16

  k_transpose<<<dim3(128, 16), 256, 0, stream>>>(conv_w, wT);
  k_prepw<<<dim3(8, 8, 9), 256, 0, stream>>>(proj_w, wq, wk, wv, wo, Wb);
  k_embed<<<NROWS, 256, 0, stream>>>(x, slice_idx, wT, conv_b, slice_emb, H0b);
  k_gemm_mfma<512, false, true><<<dim3(64, 4), 256, 0, stream>>>(H0b, Wb, H, Hb);

  for (int L = 0; L < 2; L++) {
    k_gemm_mfma<1536, false, false><<<dim3(64, 12), 256, 0, stream>>>(
        Hb, Wb + (size_t)262144 * (1 + 4 * L), QKV, nullptr);
    k_attn<<<256, 256, 0, stream>>>(QKV, Ob16);
    k_gemm_mfma<512, true, true><<<dim3(64, 4), 256, 0, stream>>>(
        Ob16, Wb + (size_t)262144 * (4 + 4 * L), H, Hb);
  }
  k_writeout<<<16384, 256, 0, stream>>>(H, out);
}

// Round 8
// 316.947 us; speedup vs baseline: 3.1683x; 1.8378x over previous
//
#include <hip/hip_runtime.h>
#include <hip/hip_bf16.h>

typedef unsigned short u16x8 __attribute__((ext_vector_type(8)));
typedef unsigned int u32x4 __attribute__((ext_vector_type(4)));
typedef __bf16 bf16x8 __attribute__((ext_vector_type(8)));
typedef float f32x4 __attribute__((ext_vector_type(4)));
typedef float f32x16 __attribute__((ext_vector_type(16)));

#define NTAP 32
#define NROWS 8192

__device__ inline unsigned short bf16bits(float f) {
  __hip_bfloat16 hb = __float2bfloat16(f);
  return __builtin_bit_cast(unsigned short, hb);
}
__device__ inline unsigned int pk2(float lo, float hi) {
  return (unsigned int)bf16bits(lo) | ((unsigned int)bf16bits(hi) << 16);
}

// ---------------- transpose conv_w (512 x 8192) -> wT (8192 x 512) fp32 ----------------
__global__ void k_transpose(const float* __restrict__ src, float* __restrict__ dst) {
  __shared__ float tile[32][65];
  int vt0 = blockIdx.x * 64;
  int de0 = blockIdx.y * 32;
  int tid = threadIdx.x;
  int vtl = tid & 63, del = tid >> 6;
#pragma unroll
  for (int p = 0; p < 8; p++)
    tile[del + 4 * p][vtl] = src[(size_t)(de0 + del + 4 * p) * 8192 + vt0 + vtl];
  __syncthreads();
  int del2 = tid & 31, vtl2 = tid >> 5;
#pragma unroll
  for (int p = 0; p < 8; p++)
    dst[(size_t)(vt0 + vtl2 + 8 * p) * 512 + de0 + del2] = tile[del2][vtl2 + 8 * p];
}

// ---------------- weights -> bf16, layout Wb[mat][n][k] ----------
__global__ void k_prepw(const float* __restrict__ proj_w, const float* __restrict__ wq,
                        const float* __restrict__ wk, const float* __restrict__ wv,
                        const float* __restrict__ wo, unsigned short* __restrict__ Wb) {
  __shared__ float tile[64][65];
  int mat = blockIdx.z;
  int n0 = blockIdx.x * 64, k0 = blockIdx.y * 64;
  int t = threadIdx.x;
  unsigned short* dst = Wb + (size_t)mat * 262144;
  if (mat == 0) {
#pragma unroll
    for (int p = 0; p < 16; p++) {
      int r = p * 4 + (t >> 6), c = t & 63;
      dst[(size_t)(n0 + r) * 512 + k0 + c] = bf16bits(proj_w[(size_t)(n0 + r) * 512 + k0 + c]);
    }
  } else {
    int idx = mat - 1, comp = idx & 3, L = idx >> 2;
    const float* srcs[4] = {wq, wk, wv, wo};
    const float* src = srcs[comp] + (size_t)L * 262144;
#pragma unroll
    for (int p = 0; p < 16; p++) {
      int r = p * 4 + (t >> 6), c = t & 63;
      tile[r][c] = src[(size_t)(k0 + r) * 512 + n0 + c];
    }
    __syncthreads();
#pragma unroll
    for (int p = 0; p < 16; p++) {
      int r = p * 4 + (t >> 6), c = t & 63;
      dst[(size_t)(n0 + r) * 512 + k0 + c] = bf16bits(tile[c][r]);
    }
  }
}

// ---------------- embed: gather conv rows + bias + slice emb -> bf16 rows ----------------
__global__ void k_embed(const int* __restrict__ x, const int* __restrict__ slice_idx,
                        const float* __restrict__ wT, const float* __restrict__ conv_b,
                        const float* __restrict__ slice_emb, unsigned short* __restrict__ H0b) {
  int r = blockIdx.x;
  int tid = threadIdx.x;
  int blk = r >> 8, l = r & 255;
  int bw = blk & 1, bh = (blk >> 1) & 1, bt = (blk >> 2) & 1, b = blk >> 3;
  int lw = l & 7, lh = (l >> 3) & 7, lt = l >> 6;
  int t = bt * 4 + lt, h = bh * 8 + lh, w = bw * 8 + lw;

  __shared__ int toks[NTAP];
  if (tid < NTAP) {
    int kt = tid >> 4, kh = (tid >> 2) & 3, kw = tid & 3;
    toks[tid] = x[((b * 16 + (2 * t + kt)) * 64 + (4 * h + kh)) * 64 + (4 * w + kw)];
  }
  __syncthreads();
  int sl = slice_idx[b];
  float acc0 = conv_b[tid] + slice_emb[sl * 512 + tid];
  float acc1 = conv_b[tid + 256] + slice_emb[sl * 512 + tid + 256];
  for (int tap = 0; tap < NTAP; tap++) {
    int v = toks[tap];
    if (v >= 0) {
      const float* wrow = wT + (size_t)(v * NTAP + tap) * 512;
      acc0 += wrow[tid];
      acc1 += wrow[tid + 256];
    }
  }
  H0b[(size_t)r * 512 + tid] = bf16bits(acc0);
  H0b[(size_t)r * 512 + tid + 256] = bf16bits(acc1);
}

// ---------------- bf16 MFMA GEMM. WM=1: Cf(f32,512)+Cb(bf16,512); WM=2: QKb/Vt split ----
template <int WM, bool RES>
__global__ void __launch_bounds__(256)
k_gemm_mfma(const unsigned short* __restrict__ A, const unsigned short* __restrict__ B,
            float* __restrict__ Cf, unsigned short* __restrict__ Cb,
            unsigned short* __restrict__ Vt) {
  __shared__ __align__(16) unsigned short As[128 * 64];
  __shared__ __align__(16) unsigned short Bs[128 * 64];
  int m0 = blockIdx.x * 128, n0 = blockIdx.y * 128;
  int tid = threadIdx.x;
  int lane = tid & 63, wid = tid >> 6;
  int wr = wid >> 1, wc = wid & 1;
  int l15 = lane & 15, lgrp = lane >> 4;
  int srow = tid >> 3, sx = tid & 7;
  f32x4 acc[4][4] = {};
  for (int k0 = 0; k0 < 512; k0 += 64) {
    u16x8 ra[4], rb[4];
#pragma unroll
    for (int i = 0; i < 4; i++) {
      int row = i * 32 + srow;
      int c = sx ^ (row & 7);
      ra[i] = *(const u16x8*)&A[(size_t)(m0 + row) * 512 + k0 + c * 8];
      rb[i] = *(const u16x8*)&B[(size_t)(n0 + row) * 512 + k0 + c * 8];
    }
    __syncthreads();
#pragma unroll
    for (int i = 0; i < 4; i++) {
      int row = i * 32 + srow;
      *(u16x8*)&As[row * 64 + sx * 8] = ra[i];
      *(u16x8*)&Bs[row * 64 + sx * 8] = rb[i];
    }
    __syncthreads();
#pragma unroll
    for (int kk = 0; kk < 2; kk++) {
      bf16x8 a[4], b[4];
#pragma unroll
      for (int m = 0; m < 4; m++) {
        int row = wr * 64 + m * 16 + l15;
        int xx = (kk * 4 + lgrp) ^ (row & 7);
        a[m] = __builtin_bit_cast(bf16x8, *(const u16x8*)&As[row * 64 + xx * 8]);
      }
#pragma unroll
      for (int n = 0; n < 4; n++) {
        int row = wc * 64 + n * 16 + l15;
        int xx = (kk * 4 + lgrp) ^ (row & 7);
        b[n] = __builtin_bit_cast(bf16x8, *(const u16x8*)&Bs[row * 64 + xx * 8]);
      }
#pragma unroll
      for (int m = 0; m < 4; m++)
#pragma unroll
        for (int n = 0; n < 4; n++)
          acc[m][n] = __builtin_amdgcn_mfma_f32_16x16x32_bf16(a[m], b[n], acc[m][n], 0, 0, 0);
    }
  }
#pragma unroll
  for (int m = 0; m < 4; m++) {
#pragma unroll
    for (int n = 0; n < 4; n++) {
      int gcol = n0 + wc * 64 + n * 16 + l15;
#pragma unroll
      for (int r = 0; r < 4; r++) {
        int grow = m0 + wr * 64 + m * 16 + lgrp * 4 + r;
        float v = acc[m][n][r];
        if (WM == 1) {
          if (RES) v += Cf[(size_t)grow * 512 + gcol];
          Cf[(size_t)grow * 512 + gcol] = v;
          Cb[(size_t)grow * 512 + gcol] = bf16bits(v);
        } else {
          if (gcol < 1024) Cb[(size_t)grow * 1024 + gcol] = bf16bits(v);
          else Vt[(size_t)(gcol - 1024) * 8192 + grow] = bf16bits(v);
        }
      }
    }
  }
}

// ---------------- MFMA flash attention: one WG (4 waves) per (block, head) --------------
// Swapped QK^T (S^T = K·Q^T), in-register softmax + P via cvt_pk/permlane32_swap,
// PV as O^T = V^T · P^T with V pre-transposed in global (Vt).
__global__ void __launch_bounds__(256)
k_attn_mfma(const unsigned short* __restrict__ QKb, const unsigned short* __restrict__ Vt,
            unsigned short* __restrict__ O16) {
  __shared__ __align__(16) unsigned short Ks[256 * 64];  // [key][d] 16B chunks swz ^(key&7)
  __shared__ __align__(16) unsigned short Vs[64 * 256];  // [dv][key] chunks swz ^(dv&7)
  int bid = blockIdx.x >> 3, head = blockIdx.x & 7;
  int r0 = bid * 256;
  int tid = threadIdx.x, lane = tid & 63, wid = tid >> 6;
  // ---- stage K (cols 512..1023 of QKb) ----
  {
    int key = tid >> 3, j = tid & 7;
#pragma unroll
    for (int p = 0; p < 8; p++) {
      int k2 = key + p * 32;
      u16x8 v = *(const u16x8*)&QKb[(size_t)(r0 + k2) * 1024 + 512 + head * 64 + j * 8];
      *(u16x8*)&Ks[k2 * 64 + ((j ^ (k2 & 7)) * 8)] = v;
    }
    int dv = tid >> 2, sg = tid & 3;
    const unsigned short* src = &Vt[(size_t)(head * 64 + dv) * 8192 + r0 + sg * 64];
#pragma unroll
    for (int c = 0; c < 8; c++) {
      u16x8 v = *(const u16x8*)&src[c * 8];
      int ch = sg * 8 + c;
      *(u16x8*)&Vs[dv * 256 + ((ch ^ (dv & 7)) * 8)] = v;
    }
  }
  int l31 = lane & 31, hi = lane >> 5;
  int qb = wid * 64;
  // ---- Q fragments in registers: qfrag[g][s], q = qb+g*32+l31, d = s*16+hi*8 ----
  bf16x8 qfrag[2][4];
#pragma unroll
  for (int g = 0; g < 2; g++)
#pragma unroll
    for (int s = 0; s < 4; s++)
      qfrag[g][s] = __builtin_bit_cast(
          bf16x8, *(const u16x8*)&QKb[(size_t)(r0 + qb + g * 32 + l31) * 1024 + head * 64 +
                                      s * 16 + hi * 8]);
  __syncthreads();

  f32x16 oacc[2][2] = {};
  float mx[2] = {-1e30f, -1e30f}, lsum[2] = {0.f, 0.f};

  for (int kt = 0; kt < 8; kt++) {
    // K A-frags: key = kt*32 + l31, chunk j = s*2 + hi
    bf16x8 kfrag[4];
    int key = kt * 32 + l31;
#pragma unroll
    for (int s = 0; s < 4; s++) {
      int j = s * 2 + hi;
      kfrag[s] = __builtin_bit_cast(bf16x8, *(const u16x8*)&Ks[key * 64 + ((j ^ (key & 7)) * 8)]);
    }
#pragma unroll
    for (int g = 0; g < 2; g++) {
      f32x16 sacc = {};
#pragma unroll
      for (int s = 0; s < 4; s++)
        sacc = __builtin_amdgcn_mfma_f32_32x32x16_bf16(kfrag[s], qfrag[g][s], sacc, 0, 0, 0);
      // lane holds S^T[key-local = (r&3)+8*(r>>2)+4*hi][q = l31], 16 regs
      float tmax = sacc[0];
#pragma unroll
      for (int r = 1; r < 16; r++) tmax = fmaxf(tmax, sacc[r]);
      tmax = fmaxf(tmax, __shfl_xor(tmax, 32, 64));
      float mn = fmaxf(mx[g], tmax);
      float sc = __expf((mx[g] - mn) * 0.125f);
      float p[16], ts = 0.f;
#pragma unroll
      for (int r = 0; r < 16; r++) {
        p[r] = __expf((sacc[r] - mn) * 0.125f);
        ts += p[r];
      }
      ts += __shfl_xor(ts, 32, 64);
      lsum[g] = lsum[g] * sc + ts;
      mx[g] = mn;
#pragma unroll
      for (int dvt = 0; dvt < 2; dvt++)
#pragma unroll
        for (int r = 0; r < 16; r++) oacc[g][dvt][r] *= sc;
      // pack P^T fragments: step st covers keys st*16..+15 (regs st*8..st*8+7)
#pragma unroll
      for (int st = 0; st < 2; st++) {
        unsigned int A = pk2(p[st * 8 + 0], p[st * 8 + 1]);
        unsigned int Bw = pk2(p[st * 8 + 2], p[st * 8 + 3]);
        unsigned int C = pk2(p[st * 8 + 4], p[st * 8 + 5]);
        unsigned int D = pk2(p[st * 8 + 6], p[st * 8 + 7]);
        asm volatile("v_permlane32_swap_b32 %0, %1" : "+v"(A), "+v"(C));
        asm volatile("v_permlane32_swap_b32 %0, %1" : "+v"(Bw), "+v"(D));
        u32x4 fw = {A, Bw, C, D};
        bf16x8 pfrag = __builtin_bit_cast(bf16x8, fw);
#pragma unroll
        for (int dvt = 0; dvt < 2; dvt++) {
          int dv = dvt * 32 + l31;
          int ch = kt * 4 + st * 2 + hi;
          bf16x8 vfrag = __builtin_bit_cast(
              bf16x8, *(const u16x8*)&Vs[dv * 256 + ((ch ^ (dv & 7)) * 8)]);
          oacc[g][dvt] = __builtin_amdgcn_mfma_f32_32x32x16_bf16(vfrag, pfrag, oacc[g][dvt], 0, 0, 0);
        }
      }
    }
  }
  // ---- write O: lane col q = l31; rows dv = dvt*32 + (r&3)+8*(r>>2)+4*hi ----
#pragma unroll
  for (int g = 0; g < 2; g++) {
    float inv = 1.f / lsum[g];
    size_t rowb = (size_t)(r0 + qb + g * 32 + l31) * 512 + head * 64;
#pragma unroll
    for (int dvt = 0; dvt < 2; dvt++)
#pragma unroll
      for (int r = 0; r < 16; r += 2) {
        int dv = dvt * 32 + (r & 3) + 8 * (r >> 2) + 4 * hi;
        unsigned int po = pk2(oacc[g][dvt][r] * inv, oacc[g][dvt][r + 1] * inv);
        *(unsigned int*)&O16[rowb + dv] = po;
      }
  }
}

// ---------------- writeout: block-major rows -> (b, d, t, h, w) f32 ----------------
__global__ void k_writeout(const float* __restrict__ H, float* __restrict__ out) {
  int idx = blockIdx.x * 256 + threadIdx.x;
  int w = idx & 15, h = (idx >> 4) & 15, t = (idx >> 8) & 7;
  int d = (idx >> 11) & 511, b = idx >> 20;
  int r = (((b * 2 + (t >> 2)) * 2 + (h >> 3)) * 2 + (w >> 3)) * 256 +
          (((t & 3) * 8 + (h & 7)) * 8 + (w & 7));
  out[idx] = H[(size_t)r * 512 + d];
}

extern "C" void kernel_launch(void* const* d_in, const int* in_sizes, int n_in,
                              void* d_out, int out_size, void* d_ws, size_t ws_size,
                              hipStream_t stream) {
  const int* x = (const int*)d_in[0];
  const int* slice_idx = (const int*)d_in[1];
  const float* conv_w = (const float*)d_in[2];
  const float* conv_b = (const float*)d_in[3];
  const float* slice_emb = (const float*)d_in[4];
  const float* proj_w = (const float*)d_in[5];
  const float* wq = (const float*)d_in[6];
  const float* wk = (const float*)d_in[7];
  const float* wv = (const float*)d_in[8];
  const float* wo = (const float*)d_in[9];
  float* out = (float*)d_out;

  float* ws = (float*)d_ws;
  // f32-word offsets:
  float* wT = ws;                                           // 16 MiB, dead after embed
  float* H = ws + 4194304;                                  // f32 trunk 16 MiB
  unsigned short* H0b = (unsigned short*)(ws + 8388608);    // 8 MiB
  unsigned short* Hb = (unsigned short*)(ws + 10485760);    // 8 MiB
  unsigned short* Ob16 = (unsigned short*)(ws + 12582912);  // 8 MiB
  unsigned short* QKb = (unsigned short*)(ws + 14680064);   // 8192x1024 bf16, 16 MiB
  unsigned short* Vt = (unsigned short*)(ws + 18874368);    // 512x8192 bf16, 8 MiB
  unsigned short* Wb = (unsigned short*)(ws + 20971520);    // 9 x 512x512 bf16, 4.5 MiB

  k_transpose<<<dim3(128, 16), 256, 0, stream>>>(conv_w, wT);
  k_prepw<<<dim3(8, 8, 9), 256, 0, stream>>>(proj_w, wq, wk, wv, wo, Wb);
  k_embed<<<NROWS, 256, 0, stream>>>(x, slice_idx, wT, conv_b, slice_emb, H0b);
  k_gemm_mfma<1, false><<<dim3(64, 4), 256, 0, stream>>>(H0b, Wb, H, Hb, nullptr);

  for (int L = 0; L < 2; L++) {
    k_gemm_mfma<2, false><<<dim3(64, 12), 256, 0, stream>>>(
        Hb, Wb + (size_t)262144 * (1 + 4 * L), nullptr, QKb, Vt);
    k_attn_mfma<<<256, 256, 0, stream>>>(QKb, Vt, Ob16);
    k_gemm_mfma<1, true><<<dim3(64, 4), 256, 0, stream>>>(
        Ob16, Wb + (size_t)262144 * (4 + 4 * L), H, Hb, nullptr);
  }
  k_writeout<<<16384, 256, 0, stream>>>(H, out);
}

// Round 9
// 267.514 us; speedup vs baseline: 3.7537x; 1.1848x over previous
//
#include <hip/hip_runtime.h>
#include <hip/hip_bf16.h>

typedef unsigned short u16x8 __attribute__((ext_vector_type(8)));
typedef unsigned int u32x4 __attribute__((ext_vector_type(4)));
typedef __bf16 bf16x8 __attribute__((ext_vector_type(8)));
typedef float f32x4 __attribute__((ext_vector_type(4)));
typedef float f32x16 __attribute__((ext_vector_type(16)));

#define NTAP 32
#define NROWS 8192

__device__ inline unsigned short bf16bits(float f) {
  __hip_bfloat16 hb = __float2bfloat16(f);
  return __builtin_bit_cast(unsigned short, hb);
}
__device__ inline unsigned int pk2(float lo, float hi) {
  return (unsigned int)bf16bits(lo) | ((unsigned int)bf16bits(hi) << 16);
}
__device__ inline float bf2f(unsigned short u) {
  return __builtin_bit_cast(float, (unsigned int)u << 16);
}

// ------- conv_w (512 x 8192 f32) -> wTb (8192 x 512 bf16), fused transpose+cast -------
__global__ void k_prepconv(const float* __restrict__ src, unsigned short* __restrict__ dst) {
  __shared__ float tile[64][65];
  int vt0 = blockIdx.x * 64, de0 = blockIdx.y * 64;
  int t = threadIdx.x;
#pragma unroll
  for (int p = 0; p < 16; p++) {
    int r = p * 4 + (t >> 6), c = t & 63;
    tile[r][c] = src[(size_t)(de0 + r) * 8192 + vt0 + c];
  }
  __syncthreads();
#pragma unroll
  for (int p = 0; p < 16; p++) {
    int r = p * 4 + (t >> 6), c = t & 63;
    dst[(size_t)(vt0 + r) * 512 + de0 + c] = bf16bits(tile[c][r]);
  }
}

// ---------------- weights -> bf16, layout Wb[mat][n][k] ----------
__global__ void k_prepw(const float* __restrict__ proj_w, const float* __restrict__ wq,
                        const float* __restrict__ wk, const float* __restrict__ wv,
                        const float* __restrict__ wo, unsigned short* __restrict__ Wb) {
  __shared__ float tile[64][65];
  int mat = blockIdx.z;
  int n0 = blockIdx.x * 64, k0 = blockIdx.y * 64;
  int t = threadIdx.x;
  unsigned short* dst = Wb + (size_t)mat * 262144;
  if (mat == 0) {
#pragma unroll
    for (int p = 0; p < 16; p++) {
      int r = p * 4 + (t >> 6), c = t & 63;
      dst[(size_t)(n0 + r) * 512 + k0 + c] = bf16bits(proj_w[(size_t)(n0 + r) * 512 + k0 + c]);
    }
  } else {
    int idx = mat - 1, comp = idx & 3, L = idx >> 2;
    const float* srcs[4] = {wq, wk, wv, wo};
    const float* src = srcs[comp] + (size_t)L * 262144;
#pragma unroll
    for (int p = 0; p < 16; p++) {
      int r = p * 4 + (t >> 6), c = t & 63;
      tile[r][c] = src[(size_t)(k0 + r) * 512 + n0 + c];
    }
    __syncthreads();
#pragma unroll
    for (int p = 0; p < 16; p++) {
      int r = p * 4 + (t >> 6), c = t & 63;
      dst[(size_t)(n0 + r) * 512 + k0 + c] = bf16bits(tile[c][r]);
    }
  }
}

// ------- embed: 4 positions/block, bf16 table gather (u16x8/lane), f32 accum -------
__global__ void k_embed(const int* __restrict__ x, const int* __restrict__ slice_idx,
                        const unsigned short* __restrict__ wTb, const float* __restrict__ conv_b,
                        const float* __restrict__ slice_emb, unsigned short* __restrict__ H0b) {
  int tid = threadIdx.x;
  int g = tid >> 6, l = tid & 63;
  int r = blockIdx.x * 4 + g;
  int blk = r >> 8, ll = r & 255;
  int bw = blk & 1, bh = (blk >> 1) & 1, bt = (blk >> 2) & 1, b = blk >> 3;
  int lw = ll & 7, lh = (ll >> 3) & 7, lt = ll >> 6;
  int t = bt * 4 + lt, h = bh * 8 + lh, w = bw * 8 + lw;

  __shared__ int toks[4][NTAP];
  if (l < NTAP) {
    int kt = l >> 4, kh = (l >> 2) & 3, kw = l & 3;
    toks[g][l] = x[((b * 16 + (2 * t + kt)) * 64 + (4 * h + kh)) * 64 + (4 * w + kw)];
  }
  __syncthreads();
  int sl = slice_idx[b];
  float4 cb0 = *(const float4*)&conv_b[l * 8];
  float4 cb1 = *(const float4*)&conv_b[l * 8 + 4];
  float4 se0 = *(const float4*)&slice_emb[sl * 512 + l * 8];
  float4 se1 = *(const float4*)&slice_emb[sl * 512 + l * 8 + 4];
  float acc[8] = {cb0.x + se0.x, cb0.y + se0.y, cb0.z + se0.z, cb0.w + se0.w,
                  cb1.x + se1.x, cb1.y + se1.y, cb1.z + se1.z, cb1.w + se1.w};
  for (int tap = 0; tap < NTAP; tap++) {
    int v = toks[g][tap];
    if (v >= 0) {
      u16x8 wv = *(const u16x8*)&wTb[(size_t)(v * NTAP + tap) * 512 + l * 8];
#pragma unroll
      for (int j = 0; j < 8; j++) acc[j] += bf2f(wv[j]);
    }
  }
  u16x8 o;
#pragma unroll
  for (int j = 0; j < 8; j++) o[j] = bf16bits(acc[j]);
  *(u16x8*)&H0b[(size_t)r * 512 + l * 8] = o;
}

// ---------------- bf16 MFMA GEMM. WM=1: Cf(f32,512)+Cb(bf16,512); WM=2: QKb/Vt split ----
template <int WM, bool RES>
__global__ void __launch_bounds__(256)
k_gemm_mfma(const unsigned short* __restrict__ A, const unsigned short* __restrict__ B,
            float* __restrict__ Cf, unsigned short* __restrict__ Cb,
            unsigned short* __restrict__ Vt) {
  __shared__ __align__(16) unsigned short As[128 * 64];
  __shared__ __align__(16) unsigned short Bs[128 * 64];
  int m0 = blockIdx.x * 128, n0 = blockIdx.y * 128;
  int tid = threadIdx.x;
  int lane = tid & 63, wid = tid >> 6;
  int wr = wid >> 1, wc = wid & 1;
  int l15 = lane & 15, lgrp = lane >> 4;
  int srow = tid >> 3, sx = tid & 7;
  f32x4 acc[4][4] = {};
  for (int k0 = 0; k0 < 512; k0 += 64) {
    u16x8 ra[4], rb[4];
#pragma unroll
    for (int i = 0; i < 4; i++) {
      int row = i * 32 + srow;
      int c = sx ^ (row & 7);
      ra[i] = *(const u16x8*)&A[(size_t)(m0 + row) * 512 + k0 + c * 8];
      rb[i] = *(const u16x8*)&B[(size_t)(n0 + row) * 512 + k0 + c * 8];
    }
    __syncthreads();
#pragma unroll
    for (int i = 0; i < 4; i++) {
      int row = i * 32 + srow;
      *(u16x8*)&As[row * 64 + sx * 8] = ra[i];
      *(u16x8*)&Bs[row * 64 + sx * 8] = rb[i];
    }
    __syncthreads();
#pragma unroll
    for (int kk = 0; kk < 2; kk++) {
      bf16x8 a[4], b[4];
#pragma unroll
      for (int m = 0; m < 4; m++) {
        int row = wr * 64 + m * 16 + l15;
        int xx = (kk * 4 + lgrp) ^ (row & 7);
        a[m] = __builtin_bit_cast(bf16x8, *(const u16x8*)&As[row * 64 + xx * 8]);
      }
#pragma unroll
      for (int n = 0; n < 4; n++) {
        int row = wc * 64 + n * 16 + l15;
        int xx = (kk * 4 + lgrp) ^ (row & 7);
        b[n] = __builtin_bit_cast(bf16x8, *(const u16x8*)&Bs[row * 64 + xx * 8]);
      }
#pragma unroll
      for (int m = 0; m < 4; m++)
#pragma unroll
        for (int n = 0; n < 4; n++)
          acc[m][n] = __builtin_amdgcn_mfma_f32_16x16x32_bf16(a[m], b[n], acc[m][n], 0, 0, 0);
    }
  }
#pragma unroll
  for (int m = 0; m < 4; m++) {
#pragma unroll
    for (int n = 0; n < 4; n++) {
      int gcol = n0 + wc * 64 + n * 16 + l15;
#pragma unroll
      for (int r = 0; r < 4; r++) {
        int grow = m0 + wr * 64 + m * 16 + lgrp * 4 + r;
        float v = acc[m][n][r];
        if (WM == 1) {
          if (RES) v += Cf[(size_t)grow * 512 + gcol];
          Cf[(size_t)grow * 512 + gcol] = v;
          Cb[(size_t)grow * 512 + gcol] = bf16bits(v);
        } else {
          if (gcol < 1024) Cb[(size_t)grow * 1024 + gcol] = bf16bits(v);
          else Vt[(size_t)(gcol - 1024) * 8192 + grow] = bf16bits(v);
        }
      }
    }
  }
}

// ---------------- MFMA flash attention: one WG (4 waves) per (block, head) --------------
__global__ void __launch_bounds__(256)
k_attn_mfma(const unsigned short* __restrict__ QKb, const unsigned short* __restrict__ Vt,
            unsigned short* __restrict__ O16) {
  __shared__ __align__(16) unsigned short Ks[256 * 64];  // [key][d] 16B chunks swz ^(key&7)
  __shared__ __align__(16) unsigned short Vs[64 * 256];  // [dv][key] chunks swz ^(dv&7)
  int bid = blockIdx.x >> 3, head = blockIdx.x & 7;
  int r0 = bid * 256;
  int tid = threadIdx.x, lane = tid & 63, wid = tid >> 6;
  {
    int key = tid >> 3, j = tid & 7;
#pragma unroll
    for (int p = 0; p < 8; p++) {
      int k2 = key + p * 32;
      u16x8 v = *(const u16x8*)&QKb[(size_t)(r0 + k2) * 1024 + 512 + head * 64 + j * 8];
      *(u16x8*)&Ks[k2 * 64 + ((j ^ (k2 & 7)) * 8)] = v;
    }
    int dv = tid >> 2, sg = tid & 3;
    const unsigned short* src = &Vt[(size_t)(head * 64 + dv) * 8192 + r0 + sg * 64];
#pragma unroll
    for (int c = 0; c < 8; c++) {
      u16x8 v = *(const u16x8*)&src[c * 8];
      int ch = sg * 8 + c;
      *(u16x8*)&Vs[dv * 256 + ((ch ^ (dv & 7)) * 8)] = v;
    }
  }
  int l31 = lane & 31, hi = lane >> 5;
  int qb = wid * 64;
  bf16x8 qfrag[2][4];
#pragma unroll
  for (int g = 0; g < 2; g++)
#pragma unroll
    for (int s = 0; s < 4; s++)
      qfrag[g][s] = __builtin_bit_cast(
          bf16x8, *(const u16x8*)&QKb[(size_t)(r0 + qb + g * 32 + l31) * 1024 + head * 64 +
                                      s * 16 + hi * 8]);
  __syncthreads();

  f32x16 oacc[2][2] = {};
  float mx[2] = {-1e30f, -1e30f}, lsum[2] = {0.f, 0.f};

  for (int kt = 0; kt < 8; kt++) {
    bf16x8 kfrag[4];
    int key = kt * 32 + l31;
#pragma unroll
    for (int s = 0; s < 4; s++) {
      int j = s * 2 + hi;
      kfrag[s] = __builtin_bit_cast(bf16x8, *(const u16x8*)&Ks[key * 64 + ((j ^ (key & 7)) * 8)]);
    }
#pragma unroll
    for (int g = 0; g < 2; g++) {
      f32x16 sacc = {};
#pragma unroll
      for (int s = 0; s < 4; s++)
        sacc = __builtin_amdgcn_mfma_f32_32x32x16_bf16(kfrag[s], qfrag[g][s], sacc, 0, 0, 0);
      float tmax = sacc[0];
#pragma unroll
      for (int r = 1; r < 16; r++) tmax = fmaxf(tmax, sacc[r]);
      tmax = fmaxf(tmax, __shfl_xor(tmax, 32, 64));
      float mn = fmaxf(mx[g], tmax);
      float sc = __expf((mx[g] - mn) * 0.125f);
      float p[16], ts = 0.f;
#pragma unroll
      for (int r = 0; r < 16; r++) {
        p[r] = __expf((sacc[r] - mn) * 0.125f);
        ts += p[r];
      }
      ts += __shfl_xor(ts, 32, 64);
      lsum[g] = lsum[g] * sc + ts;
      mx[g] = mn;
#pragma unroll
      for (int dvt = 0; dvt < 2; dvt++)
#pragma unroll
        for (int r = 0; r < 16; r++) oacc[g][dvt][r] *= sc;
#pragma unroll
      for (int st = 0; st < 2; st++) {
        unsigned int A = pk2(p[st * 8 + 0], p[st * 8 + 1]);
        unsigned int Bw = pk2(p[st * 8 + 2], p[st * 8 + 3]);
        unsigned int C = pk2(p[st * 8 + 4], p[st * 8 + 5]);
        unsigned int D = pk2(p[st * 8 + 6], p[st * 8 + 7]);
        asm volatile("v_permlane32_swap_b32 %0, %1" : "+v"(A), "+v"(C));
        asm volatile("v_permlane32_swap_b32 %0, %1" : "+v"(Bw), "+v"(D));
        u32x4 fw = {A, Bw, C, D};
        bf16x8 pfrag = __builtin_bit_cast(bf16x8, fw);
#pragma unroll
        for (int dvt = 0; dvt < 2; dvt++) {
          int dv = dvt * 32 + l31;
          int ch = kt * 4 + st * 2 + hi;
          bf16x8 vfrag = __builtin_bit_cast(
              bf16x8, *(const u16x8*)&Vs[dv * 256 + ((ch ^ (dv & 7)) * 8)]);
          oacc[g][dvt] = __builtin_amdgcn_mfma_f32_32x32x16_bf16(vfrag, pfrag, oacc[g][dvt], 0, 0, 0);
        }
      }
    }
  }
#pragma unroll
  for (int g = 0; g < 2; g++) {
    float inv = 1.f / lsum[g];
    size_t rowb = (size_t)(r0 + qb + g * 32 + l31) * 512 + head * 64;
#pragma unroll
    for (int dvt = 0; dvt < 2; dvt++)
#pragma unroll
      for (int r = 0; r < 16; r += 2) {
        int dv = dvt * 32 + (r & 3) + 8 * (r >> 2) + 4 * hi;
        unsigned int po = pk2(oacc[g][dvt][r] * inv, oacc[g][dvt][r + 1] * inv);
        *(unsigned int*)&O16[rowb + dv] = po;
      }
  }
}

// ------- writeout v2: LDS transpose; coalesced H reads, full-line out writes -------
// grid (16, 16): x = (b*2+bt)*2+bh, y = 32-d group.
__global__ void k_writeout(const float* __restrict__ H, float* __restrict__ out) {
  __shared__ float t[512][33];
  int bp = blockIdx.x;
  int d0 = blockIdx.y * 32;
  int tid = threadIdx.x;
  int base_row = bp * 512;
#pragma unroll
  for (int i = 0; i < 16; i++) {
    int id = i * 256 + tid;
    int r = id >> 3, c = id & 7;
    float4 v = *(const float4*)&H[(size_t)(base_row + r) * 512 + d0 + c * 4];
    t[r][c * 4 + 0] = v.x;
    t[r][c * 4 + 1] = v.y;
    t[r][c * 4 + 2] = v.z;
    t[r][c * 4 + 3] = v.w;
  }
  __syncthreads();
  int b = bp >> 2, bt = (bp >> 1) & 1, bh = bp & 1;
  int w = tid & 15, lh = (tid >> 4) & 7, ltl = tid >> 7;
  int lw = w & 7, bw = w >> 3;
#pragma unroll
  for (int dd = 0; dd < 32; dd++) {
#pragma unroll
    for (int s = 0; s < 2; s++) {
      int lt = s * 2 + ltl;
      int pos = bw * 256 + lt * 64 + lh * 8 + lw;
      out[((size_t)(b * 512 + d0 + dd) * 8 + bt * 4 + lt) * 256 + (bh * 8 + lh) * 16 + w] =
          t[pos][dd];
    }
  }
}

extern "C" void kernel_launch(void* const* d_in, const int* in_sizes, int n_in,
                              void* d_out, int out_size, void* d_ws, size_t ws_size,
                              hipStream_t stream) {
  const int* x = (const int*)d_in[0];
  const int* slice_idx = (const int*)d_in[1];
  const float* conv_w = (const float*)d_in[2];
  const float* conv_b = (const float*)d_in[3];
  const float* slice_emb = (const float*)d_in[4];
  const float* proj_w = (const float*)d_in[5];
  const float* wq = (const float*)d_in[6];
  const float* wk = (const float*)d_in[7];
  const float* wv = (const float*)d_in[8];
  const float* wo = (const float*)d_in[9];
  float* out = (float*)d_out;

  float* ws = (float*)d_ws;
  unsigned short* wTb = (unsigned short*)ws;                // 8192x512 bf16, 8 MiB
  float* H = ws + 4194304;                                  // f32 trunk 16 MiB
  unsigned short* H0b = (unsigned short*)(ws + 8388608);    // 8 MiB
  unsigned short* Hb = (unsigned short*)(ws + 10485760);    // 8 MiB
  unsigned short* Ob16 = (unsigned short*)(ws + 12582912);  // 8 MiB
  unsigned short* QKb = (unsigned short*)(ws + 14680064);   // 8192x1024 bf16, 16 MiB
  unsigned short* Vt = (unsigned short*)(ws + 18874368);    // 512x8192 bf16, 8 MiB
  unsigned short* Wb = (unsigned short*)(ws + 20971520);    // 9 x 512x512 bf16, 4.5 MiB

  k_prepconv<<<dim3(128, 8), 256, 0, stream>>>(conv_w, wTb);
  k_prepw<<<dim3(8, 8, 9), 256, 0, stream>>>(proj_w, wq, wk, wv, wo, Wb);
  k_embed<<<2048, 256, 0, stream>>>(x, slice_idx, wTb, conv_b, slice_emb, H0b);
  k_gemm_mfma<1, false><<<dim3(64, 4), 256, 0, stream>>>(H0b, Wb, H, Hb, nullptr);

  for (int L = 0; L < 2; L++) {
    k_gemm_mfma<2, false><<<dim3(64, 12), 256, 0, stream>>>(
        Hb, Wb + (size_t)262144 * (1 + 4 * L), nullptr, QKb, Vt);
    k_attn_mfma<<<256, 256, 0, stream>>>(QKb, Vt, Ob16);
    k_gemm_mfma<1, true><<<dim3(64, 4), 256, 0, stream>>>(
        Ob16, Wb + (size_t)262144 * (4 + 4 * L), H, Hb, nullptr);
  }
  k_writeout<<<dim3(16, 16), 256, 0, stream>>>(H, out);
}

// Round 11
// 265.842 us; speedup vs baseline: 3.7773x; 1.0063x over previous
//
#include <hip/hip_runtime.h>
#include <hip/hip_bf16.h>

typedef unsigned short u16x8 __attribute__((ext_vector_type(8)));
typedef unsigned int u32x4 __attribute__((ext_vector_type(4)));
typedef __bf16 bf16x8 __attribute__((ext_vector_type(8)));
typedef float f32x4 __attribute__((ext_vector_type(4)));
typedef float f32x16 __attribute__((ext_vector_type(16)));

#define NTAP 32
#define NROWS 8192

__device__ inline unsigned short bf16bits(float f) {
  __hip_bfloat16 hb = __float2bfloat16(f);
  return __builtin_bit_cast(unsigned short, hb);
}
__device__ inline unsigned int pk2(float lo, float hi) {
  return (unsigned int)bf16bits(lo) | ((unsigned int)bf16bits(hi) << 16);
}
__device__ inline float bf2f(unsigned short u) {
  return __builtin_bit_cast(float, (unsigned int)u << 16);
}

// ------- fused weight prep: conv_w transpose+cast AND attn/proj weights -> bf16 -------
// grid.x = 1600: [0,1024) conv tiles; [1024,1600) weight tiles (9 mats x 64).
__global__ void k_prep(const float* __restrict__ conv_w, const float* __restrict__ proj_w,
                       const float* __restrict__ wq, const float* __restrict__ wk,
                       const float* __restrict__ wv, const float* __restrict__ wo,
                       unsigned short* __restrict__ wTb, unsigned short* __restrict__ Wb) {
  __shared__ float tile[64][65];
  int bid = blockIdx.x;
  int t = threadIdx.x;
  if (bid < 1024) {
    int vt0 = (bid & 127) * 64, de0 = (bid >> 7) * 64;
#pragma unroll
    for (int p = 0; p < 16; p++) {
      int r = p * 4 + (t >> 6), c = t & 63;
      tile[r][c] = conv_w[(size_t)(de0 + r) * 8192 + vt0 + c];
    }
    __syncthreads();
#pragma unroll
    for (int p = 0; p < 16; p++) {
      int r = p * 4 + (t >> 6), c = t & 63;
      wTb[(size_t)(vt0 + r) * 512 + de0 + c] = bf16bits(tile[c][r]);
    }
  } else {
    int wid2 = bid - 1024;
    int mat = wid2 >> 6, rem = wid2 & 63;
    int n0 = (rem & 7) * 64, k0 = (rem >> 3) * 64;
    unsigned short* dst = Wb + (size_t)mat * 262144;
    if (mat == 0) {
#pragma unroll
      for (int p = 0; p < 16; p++) {
        int r = p * 4 + (t >> 6), c = t & 63;
        dst[(size_t)(n0 + r) * 512 + k0 + c] = bf16bits(proj_w[(size_t)(n0 + r) * 512 + k0 + c]);
      }
    } else {
      int idx = mat - 1, comp = idx & 3, L = idx >> 2;
      const float* srcs[4] = {wq, wk, wv, wo};
      const float* src = srcs[comp] + (size_t)L * 262144;
#pragma unroll
      for (int p = 0; p < 16; p++) {
        int r = p * 4 + (t >> 6), c = t & 63;
        tile[r][c] = src[(size_t)(k0 + r) * 512 + n0 + c];
      }
      __syncthreads();
#pragma unroll
      for (int p = 0; p < 16; p++) {
        int r = p * 4 + (t >> 6), c = t & 63;
        dst[(size_t)(n0 + r) * 512 + k0 + c] = bf16bits(tile[c][r]);
      }
    }
  }
}

// ------- embed: 4 positions/block, bf16 table gather (u16x8/lane), f32 accum -------
__global__ void k_embed(const int* __restrict__ x, const int* __restrict__ slice_idx,
                        const unsigned short* __restrict__ wTb, const float* __restrict__ conv_b,
                        const float* __restrict__ slice_emb, unsigned short* __restrict__ H0b) {
  int tid = threadIdx.x;
  int g = tid >> 6, l = tid & 63;
  int r = blockIdx.x * 4 + g;
  int blk = r >> 8, ll = r & 255;
  int bw = blk & 1, bh = (blk >> 1) & 1, bt = (blk >> 2) & 1, b = blk >> 3;
  int lw = ll & 7, lh = (ll >> 3) & 7, lt = ll >> 6;
  int t = bt * 4 + lt, h = bh * 8 + lh, w = bw * 8 + lw;

  __shared__ int toks[4][NTAP];
  if (l < NTAP) {
    int kt = l >> 4, kh = (l >> 2) & 3, kw = l & 3;
    toks[g][l] = x[((b * 16 + (2 * t + kt)) * 64 + (4 * h + kh)) * 64 + (4 * w + kw)];
  }
  __syncthreads();
  int sl = slice_idx[b];
  float4 cb0 = *(const float4*)&conv_b[l * 8];
  float4 cb1 = *(const float4*)&conv_b[l * 8 + 4];
  float4 se0 = *(const float4*)&slice_emb[sl * 512 + l * 8];
  float4 se1 = *(const float4*)&slice_emb[sl * 512 + l * 8 + 4];
  float acc[8] = {cb0.x + se0.x, cb0.y + se0.y, cb0.z + se0.z, cb0.w + se0.w,
                  cb1.x + se1.x, cb1.y + se1.y, cb1.z + se1.z, cb1.w + se1.w};
  for (int tap = 0; tap < NTAP; tap++) {
    int v = toks[g][tap];
    if (v >= 0) {
      u16x8 wv = *(const u16x8*)&wTb[(size_t)(v * NTAP + tap) * 512 + l * 8];
#pragma unroll
      for (int j = 0; j < 8; j++) acc[j] += bf2f(wv[j]);
    }
  }
  u16x8 o;
#pragma unroll
  for (int j = 0; j < 8; j++) o[j] = bf16bits(acc[j]);
  *(u16x8*)&H0b[(size_t)r * 512 + l * 8] = o;
}

// ---------------- bf16 MFMA GEMM. WM=1: Cf(f32,512)+Cb(bf16,512); WM=2: QKb + Vt -------
// WM=2 V-tiles (n0>=1024) do an LDS transpose so Vt writes are coalesced.
template <int WM, bool RES>
__global__ void __launch_bounds__(256)
k_gemm_mfma(const unsigned short* __restrict__ A, const unsigned short* __restrict__ B,
            float* __restrict__ Cf, unsigned short* __restrict__ Cb,
            unsigned short* __restrict__ Vt) {
  struct ABb { unsigned short As[128 * 64]; unsigned short Bs[128 * 64]; };
  union SMu { ABb ab; unsigned short T[64][136]; };
  __shared__ __align__(16) SMu sm;
  unsigned short* As = sm.ab.As;
  unsigned short* Bs = sm.ab.Bs;
  int m0 = blockIdx.x * 128, n0 = blockIdx.y * 128;
  int tid = threadIdx.x;
  int lane = tid & 63, wid = tid >> 6;
  int wr = wid >> 1, wc = wid & 1;
  int l15 = lane & 15, lgrp = lane >> 4;
  int srow = tid >> 3, sx = tid & 7;
  f32x4 acc[4][4] = {};
  for (int k0 = 0; k0 < 512; k0 += 64) {
    u16x8 ra[4], rb[4];
#pragma unroll
    for (int i = 0; i < 4; i++) {
      int row = i * 32 + srow;
      int c = sx ^ (row & 7);
      ra[i] = *(const u16x8*)&A[(size_t)(m0 + row) * 512 + k0 + c * 8];
      rb[i] = *(const u16x8*)&B[(size_t)(n0 + row) * 512 + k0 + c * 8];
    }
    __syncthreads();
#pragma unroll
    for (int i = 0; i < 4; i++) {
      int row = i * 32 + srow;
      *(u16x8*)&As[row * 64 + sx * 8] = ra[i];
      *(u16x8*)&Bs[row * 64 + sx * 8] = rb[i];
    }
    __syncthreads();
#pragma unroll
    for (int kk = 0; kk < 2; kk++) {
      bf16x8 a[4], b[4];
#pragma unroll
      for (int m = 0; m < 4; m++) {
        int row = wr * 64 + m * 16 + l15;
        int xx = (kk * 4 + lgrp) ^ (row & 7);
        a[m] = __builtin_bit_cast(bf16x8, *(const u16x8*)&As[row * 64 + xx * 8]);
      }
#pragma unroll
      for (int n = 0; n < 4; n++) {
        int row = wc * 64 + n * 16 + l15;
        int xx = (kk * 4 + lgrp) ^ (row & 7);
        b[n] = __builtin_bit_cast(bf16x8, *(const u16x8*)&Bs[row * 64 + xx * 8]);
      }
#pragma unroll
      for (int m = 0; m < 4; m++)
#pragma unroll
        for (int n = 0; n < 4; n++)
          acc[m][n] = __builtin_amdgcn_mfma_f32_16x16x32_bf16(a[m], b[n], acc[m][n], 0, 0, 0);
    }
  }
  if (WM == 2 && n0 >= 1024) {
    // V-tile: transpose 128x128 via LDS (2 passes of 64 cols), write Vt coalesced.
    __syncthreads();
#pragma unroll
    for (int p = 0; p < 2; p++) {
      if (wc == p) {
#pragma unroll
        for (int m = 0; m < 4; m++)
#pragma unroll
          for (int n = 0; n < 4; n++)
#pragma unroll
            for (int r = 0; r < 4; r++)
              sm.T[n * 16 + l15][wr * 64 + m * 16 + lgrp * 4 + r] = bf16bits(acc[m][n][r]);
      }
      __syncthreads();
      int c = tid >> 2, rcb = tid & 3;
#pragma unroll
      for (int it = 0; it < 4; it++) {
        int rc = it * 4 + rcb;
        *(u16x8*)&Vt[(size_t)(n0 - 1024 + p * 64 + c) * 8192 + m0 + rc * 8] =
            *(const u16x8*)&sm.T[c][rc * 8];
      }
      if (p == 0) __syncthreads();
    }
    return;
  }
#pragma unroll
  for (int m = 0; m < 4; m++) {
#pragma unroll
    for (int n = 0; n < 4; n++) {
      int gcol = n0 + wc * 64 + n * 16 + l15;
#pragma unroll
      for (int r = 0; r < 4; r++) {
        int grow = m0 + wr * 64 + m * 16 + lgrp * 4 + r;
        float v = acc[m][n][r];
        if (WM == 1) {
          if (RES) v += Cf[(size_t)grow * 512 + gcol];
          Cf[(size_t)grow * 512 + gcol] = v;
          Cb[(size_t)grow * 512 + gcol] = bf16bits(v);
        } else {
          Cb[(size_t)grow * 1024 + gcol] = bf16bits(v);
        }
      }
    }
  }
}

// ------- MFMA flash attention, q-split: one WG (4 waves) per (block, head, q-half) ------
// grid 512 -> 2 WGs/CU. Each wave: 32 q rows; K/V staged full per WG.
__global__ void __launch_bounds__(256)
k_attn_mfma(const unsigned short* __restrict__ QKb, const unsigned short* __restrict__ Vt,
            unsigned short* __restrict__ O16) {
  __shared__ __align__(16) unsigned short Ks[256 * 64];  // [key][d] swz ^(key&7)
  __shared__ __align__(16) unsigned short Vs[64 * 256];  // [dv][key] swz ^(dv&7)
  int xg = blockIdx.x;
  int bid = xg >> 4, head = (xg >> 1) & 7, qh = xg & 1;
  int r0 = bid * 256;
  int tid = threadIdx.x, lane = tid & 63, wid = tid >> 6;
  {
    int key = tid >> 3, j = tid & 7;
#pragma unroll
    for (int p = 0; p < 8; p++) {
      int k2 = key + p * 32;
      u16x8 v = *(const u16x8*)&QKb[(size_t)(r0 + k2) * 1024 + 512 + head * 64 + j * 8];
      *(u16x8*)&Ks[k2 * 64 + ((j ^ (k2 & 7)) * 8)] = v;
    }
    int dv = tid >> 2, sg = tid & 3;
    const unsigned short* src = &Vt[(size_t)(head * 64 + dv) * 8192 + r0 + sg * 64];
#pragma unroll
    for (int c = 0; c < 8; c++) {
      u16x8 v = *(const u16x8*)&src[c * 8];
      int ch = sg * 8 + c;
      *(u16x8*)&Vs[dv * 256 + ((ch ^ (dv & 7)) * 8)] = v;
    }
  }
  int l31 = lane & 31, hi = lane >> 5;
  int q = r0 + qh * 128 + wid * 32 + l31;
  bf16x8 qfrag[4];
#pragma unroll
  for (int s = 0; s < 4; s++)
    qfrag[s] = __builtin_bit_cast(
        bf16x8, *(const u16x8*)&QKb[(size_t)q * 1024 + head * 64 + s * 16 + hi * 8]);
  __syncthreads();

  f32x16 oacc[2] = {};
  float mx = -1e30f, lsum = 0.f;

  for (int kt = 0; kt < 8; kt++) {
    bf16x8 kfrag[4];
    int key = kt * 32 + l31;
#pragma unroll
    for (int s = 0; s < 4; s++) {
      int j = s * 2 + hi;
      kfrag[s] = __builtin_bit_cast(bf16x8, *(const u16x8*)&Ks[key * 64 + ((j ^ (key & 7)) * 8)]);
    }
    f32x16 sacc = {};
#pragma unroll
    for (int s = 0; s < 4; s++)
      sacc = __builtin_amdgcn_mfma_f32_32x32x16_bf16(kfrag[s], qfrag[s], sacc, 0, 0, 0);
    float tmax = sacc[0];
#pragma unroll
    for (int r = 1; r < 16; r++) tmax = fmaxf(tmax, sacc[r]);
    tmax = fmaxf(tmax, __shfl_xor(tmax, 32, 64));
    float mn = fmaxf(mx, tmax);
    float sc = __expf((mx - mn) * 0.125f);
    float p[16], ts = 0.f;
#pragma unroll
    for (int r = 0; r < 16; r++) {
      p[r] = __expf((sacc[r] - mn) * 0.125f);
      ts += p[r];
    }
    ts += __shfl_xor(ts, 32, 64);
    lsum = lsum * sc + ts;
    mx = mn;
#pragma unroll
    for (int dvt = 0; dvt < 2; dvt++)
#pragma unroll
      for (int r = 0; r < 16; r++) oacc[dvt][r] *= sc;
#pragma unroll
    for (int st = 0; st < 2; st++) {
      unsigned int Aw = pk2(p[st * 8 + 0], p[st * 8 + 1]);
      unsigned int Bw = pk2(p[st * 8 + 2], p[st * 8 + 3]);
      unsigned int Cw = pk2(p[st * 8 + 4], p[st * 8 + 5]);
      unsigned int Dw = pk2(p[st * 8 + 6], p[st * 8 + 7]);
      asm volatile("v_permlane32_swap_b32 %0, %1" : "+v"(Aw), "+v"(Cw));
      asm volatile("v_permlane32_swap_b32 %0, %1" : "+v"(Bw), "+v"(Dw));
      u32x4 fw = {Aw, Bw, Cw, Dw};
      bf16x8 pfrag = __builtin_bit_cast(bf16x8, fw);
#pragma unroll
      for (int dvt = 0; dvt < 2; dvt++) {
        int dv = dvt * 32 + l31;
        int ch = kt * 4 + st * 2 + hi;
        bf16x8 vfrag = __builtin_bit_cast(
            bf16x8, *(const u16x8*)&Vs[dv * 256 + ((ch ^ (dv & 7)) * 8)]);
        oacc[dvt] = __builtin_amdgcn_mfma_f32_32x32x16_bf16(vfrag, pfrag, oacc[dvt], 0, 0, 0);
      }
    }
  }
  float inv = 1.f / lsum;
  size_t rowb = (size_t)q * 512 + head * 64;
#pragma unroll
  for (int dvt = 0; dvt < 2; dvt++)
#pragma unroll
    for (int r = 0; r < 16; r += 2) {
      int dv = dvt * 32 + (r & 3) + 8 * (r >> 2) + 4 * hi;
      unsigned int po = pk2(oacc[dvt][r] * inv, oacc[dvt][r + 1] * inv);
      *(unsigned int*)&O16[rowb + dv] = po;
    }
}

// ------- writeout: LDS transpose; coalesced H reads, full-line out writes -------
__global__ void k_writeout(const float* __restrict__ H, float* __restrict__ out) {
  __shared__ float t[512][33];
  int bp = blockIdx.x;
  int d0 = blockIdx.y * 32;
  int tid = threadIdx.x;
  int base_row = bp * 512;
#pragma unroll
  for (int i = 0; i < 16; i++) {
    int id = i * 256 + tid;
    int r = id >> 3, c = id & 7;
    float4 v = *(const float4*)&H[(size_t)(base_row + r) * 512 + d0 + c * 4];
    t[r][c * 4 + 0] = v.x;
    t[r][c * 4 + 1] = v.y;
    t[r][c * 4 + 2] = v.z;
    t[r][c * 4 + 3] = v.w;
  }
  __syncthreads();
  int b = bp >> 2, bt = (bp >> 1) & 1, bh = bp & 1;
  int w = tid & 15, lh = (tid >> 4) & 7, ltl = tid >> 7;
  int lw = w & 7, bw = w >> 3;
#pragma unroll
  for (int dd = 0; dd < 32; dd++) {
#pragma unroll
    for (int s = 0; s < 2; s++) {
      int lt = s * 2 + ltl;
      int pos = bw * 256 + lt * 64 + lh * 8 + lw;
      out[((size_t)(b * 512 + d0 + dd) * 8 + bt * 4 + lt) * 256 + (bh * 8 + lh) * 16 + w] =
          t[pos][dd];
    }
  }
}

extern "C" void kernel_launch(void* const* d_in, const int* in_sizes, int n_in,
                              void* d_out, int out_size, void* d_ws, size_t ws_size,
                              hipStream_t stream) {
  const int* x = (const int*)d_in[0];
  const int* slice_idx = (const int*)d_in[1];
  const float* conv_w = (const float*)d_in[2];
  const float* conv_b = (const float*)d_in[3];
  const float* slice_emb = (const float*)d_in[4];
  const float* proj_w = (const float*)d_in[5];
  const float* wq = (const float*)d_in[6];
  const float* wk = (const float*)d_in[7];
  const float* wv = (const float*)d_in[8];
  const float* wo = (const float*)d_in[9];
  float* out = (float*)d_out;

  float* ws = (float*)d_ws;
  unsigned short* wTb = (unsigned short*)ws;                // 8192x512 bf16, 8 MiB
  float* H = ws + 4194304;                                  // f32 trunk 16 MiB
  unsigned short* H0b = (unsigned short*)(ws + 8388608);    // 8 MiB
  unsigned short* Hb = (unsigned short*)(ws + 10485760);    // 8 MiB
  unsigned short* Ob16 = (unsigned short*)(ws + 12582912);  // 8 MiB
  unsigned short* QKb = (unsigned short*)(ws + 14680064);   // 8192x1024 bf16, 16 MiB
  unsigned short* Vt = (unsigned short*)(ws + 18874368);    // 512x8192 bf16, 8 MiB
  unsigned short* Wb = (unsigned short*)(ws + 20971520);    // 9 x 512x512 bf16, 4.5 MiB

  k_prep<<<1600, 256, 0, stream>>>(conv_w, proj_w, wq, wk, wv, wo, wTb, Wb);
  k_embed<<<2048, 256, 0, stream>>>(x, slice_idx, wTb, conv_b, slice_emb, H0b);
  k_gemm_mfma<1, false><<<dim3(64, 4), 256, 0, stream>>>(H0b, Wb, H, Hb, nullptr);

  for (int L = 0; L < 2; L++) {
    k_gemm_mfma<2, false><<<dim3(64, 12), 256, 0, stream>>>(
        Hb, Wb + (size_t)262144 * (1 + 4 * L), nullptr, QKb, Vt);
    k_attn_mfma<<<512, 256, 0, stream>>>(QKb, Vt, Ob16);
    k_gemm_mfma<1, true><<<dim3(64, 4), 256, 0, stream>>>(
        Ob16, Wb + (size_t)262144 * (4 + 4 * L), H, Hb, nullptr);
  }
  k_writeout<<<dim3(16, 16), 256, 0, stream>>>(H, out);
}

// Round 13
// 247.075 us; speedup vs baseline: 4.0643x; 1.0760x over previous
//
#include <hip/hip_runtime.h>
#include <hip/hip_bf16.h>

typedef unsigned short u16x8 __attribute__((ext_vector_type(8)));
typedef unsigned int u32x4 __attribute__((ext_vector_type(4)));
typedef __bf16 bf16x8 __attribute__((ext_vector_type(8)));
typedef float f32x4 __attribute__((ext_vector_type(4)));
typedef float f32x16 __attribute__((ext_vector_type(16)));

#define NTAP 32
#define NROWS 8192

__device__ inline unsigned short bf16bits(float f) {
  __hip_bfloat16 hb = __float2bfloat16(f);
  return __builtin_bit_cast(unsigned short, hb);
}
__device__ inline unsigned int pk2(float lo, float hi) {
  return (unsigned int)bf16bits(lo) | ((unsigned int)bf16bits(hi) << 16);
}
__device__ inline float bf2f(unsigned short u) {
  return __builtin_bit_cast(float, (unsigned int)u << 16);
}

// ------- fused weight prep: conv_w transpose+cast AND attn/proj weights -> bf16 -------
__global__ void k_prep(const float* __restrict__ conv_w, const float* __restrict__ proj_w,
                       const float* __restrict__ wq, const float* __restrict__ wk,
                       const float* __restrict__ wv, const float* __restrict__ wo,
                       unsigned short* __restrict__ wTb, unsigned short* __restrict__ Wb) {
  __shared__ float tile[64][65];
  int bid = blockIdx.x;
  int t = threadIdx.x;
  if (bid < 1024) {
    int vt0 = (bid & 127) * 64, de0 = (bid >> 7) * 64;
#pragma unroll
    for (int p = 0; p < 16; p++) {
      int r = p * 4 + (t >> 6), c = t & 63;
      tile[r][c] = conv_w[(size_t)(de0 + r) * 8192 + vt0 + c];
    }
    __syncthreads();
#pragma unroll
    for (int p = 0; p < 16; p++) {
      int r = p * 4 + (t >> 6), c = t & 63;
      wTb[(size_t)(vt0 + r) * 512 + de0 + c] = bf16bits(tile[c][r]);
    }
  } else {
    int wid2 = bid - 1024;
    int mat = wid2 >> 6, rem = wid2 & 63;
    int n0 = (rem & 7) * 64, k0 = (rem >> 3) * 64;
    unsigned short* dst = Wb + (size_t)mat * 262144;
    if (mat == 0) {
#pragma unroll
      for (int p = 0; p < 16; p++) {
        int r = p * 4 + (t >> 6), c = t & 63;
        dst[(size_t)(n0 + r) * 512 + k0 + c] = bf16bits(proj_w[(size_t)(n0 + r) * 512 + k0 + c]);
      }
    } else {
      int idx = mat - 1, comp = idx & 3, L = idx >> 2;
      const float* srcs[4] = {wq, wk, wv, wo};
      const float* src = srcs[comp] + (size_t)L * 262144;
#pragma unroll
      for (int p = 0; p < 16; p++) {
        int r = p * 4 + (t >> 6), c = t & 63;
        tile[r][c] = src[(size_t)(k0 + r) * 512 + n0 + c];
      }
      __syncthreads();
#pragma unroll
      for (int p = 0; p < 16; p++) {
        int r = p * 4 + (t >> 6), c = t & 63;
        dst[(size_t)(n0 + r) * 512 + k0 + c] = bf16bits(tile[c][r]);
      }
    }
  }
}

// ------- embed: 4 positions/block, bf16 table gather (u16x8/lane), f32 accum -------
__global__ void k_embed(const int* __restrict__ x, const int* __restrict__ slice_idx,
                        const unsigned short* __restrict__ wTb, const float* __restrict__ conv_b,
                        const float* __restrict__ slice_emb, unsigned short* __restrict__ H0b) {
  int tid = threadIdx.x;
  int g = tid >> 6, l = tid & 63;
  int r = blockIdx.x * 4 + g;
  int blk = r >> 8, ll = r & 255;
  int bw = blk & 1, bh = (blk >> 1) & 1, bt = (blk >> 2) & 1, b = blk >> 3;
  int lw = ll & 7, lh = (ll >> 3) & 7, lt = ll >> 6;
  int t = bt * 4 + lt, h = bh * 8 + lh, w = bw * 8 + lw;

  __shared__ int toks[4][NTAP];
  if (l < NTAP) {
    int kt = l >> 4, kh = (l >> 2) & 3, kw = l & 3;
    toks[g][l] = x[((b * 16 + (2 * t + kt)) * 64 + (4 * h + kh)) * 64 + (4 * w + kw)];
  }
  __syncthreads();
  int sl = slice_idx[b];
  float4 cb0 = *(const float4*)&conv_b[l * 8];
  float4 cb1 = *(const float4*)&conv_b[l * 8 + 4];
  float4 se0 = *(const float4*)&slice_emb[sl * 512 + l * 8];
  float4 se1 = *(const float4*)&slice_emb[sl * 512 + l * 8 + 4];
  float acc[8] = {cb0.x + se0.x, cb0.y + se0.y, cb0.z + se0.z, cb0.w + se0.w,
                  cb1.x + se1.x, cb1.y + se1.y, cb1.z + se1.z, cb1.w + se1.w};
  for (int tap = 0; tap < NTAP; tap++) {
    int v = toks[g][tap];
    if (v >= 0) {
      u16x8 wv = *(const u16x8*)&wTb[(size_t)(v * NTAP + tap) * 512 + l * 8];
#pragma unroll
      for (int j = 0; j < 8; j++) acc[j] += bf2f(wv[j]);
    }
  }
  u16x8 o;
#pragma unroll
  for (int j = 0; j < 8; j++) o[j] = bf16bits(acc[j]);
  *(u16x8*)&H0b[(size_t)r * 512 + l * 8] = o;
}

// ---------------- bf16 MFMA GEMM with K-prefetch. WM=1: Cf+Cb; WM=2: QKb + transposed Vt.
template <int WM, bool RES>
__global__ void __launch_bounds__(256)
k_gemm_mfma(const unsigned short* __restrict__ A, const unsigned short* __restrict__ B,
            float* __restrict__ Cf, unsigned short* __restrict__ Cb,
            unsigned short* __restrict__ Vt) {
  struct ABb { unsigned short As[128 * 64]; unsigned short Bs[128 * 64]; };
  union SMu { ABb ab; unsigned short T[64][136]; };
  __shared__ __align__(16) SMu sm;
  unsigned short* As = sm.ab.As;
  unsigned short* Bs = sm.ab.Bs;
  int m0 = blockIdx.x * 128, n0 = blockIdx.y * 128;
  int tid = threadIdx.x;
  int lane = tid & 63, wid = tid >> 6;
  int wr = wid >> 1, wc = wid & 1;
  int l15 = lane & 15, lgrp = lane >> 4;
  int srow = tid >> 3, sx = tid & 7;
  f32x4 acc[4][4] = {};
  u16x8 ra[4], rb[4];
#pragma unroll
  for (int i = 0; i < 4; i++) {
    int row = i * 32 + srow;
    int c = sx ^ (row & 7);
    ra[i] = *(const u16x8*)&A[(size_t)(m0 + row) * 512 + c * 8];
    rb[i] = *(const u16x8*)&B[(size_t)(n0 + row) * 512 + c * 8];
  }
  for (int k0 = 0; k0 < 512; k0 += 64) {
    __syncthreads();  // previous iteration's LDS readers done
#pragma unroll
    for (int i = 0; i < 4; i++) {
      int row = i * 32 + srow;
      *(u16x8*)&As[row * 64 + sx * 8] = ra[i];
      *(u16x8*)&Bs[row * 64 + sx * 8] = rb[i];
    }
    __syncthreads();
    if (k0 + 64 < 512) {  // prefetch next K-tile; completes under the MFMA section
#pragma unroll
      for (int i = 0; i < 4; i++) {
        int row = i * 32 + srow;
        int c = sx ^ (row & 7);
        ra[i] = *(const u16x8*)&A[(size_t)(m0 + row) * 512 + k0 + 64 + c * 8];
        rb[i] = *(const u16x8*)&B[(size_t)(n0 + row) * 512 + k0 + 64 + c * 8];
      }
    }
#pragma unroll
    for (int kk = 0; kk < 2; kk++) {
      bf16x8 a[4], b[4];
#pragma unroll
      for (int m = 0; m < 4; m++) {
        int row = wr * 64 + m * 16 + l15;
        int xx = (kk * 4 + lgrp) ^ (row & 7);
        a[m] = __builtin_bit_cast(bf16x8, *(const u16x8*)&As[row * 64 + xx * 8]);
      }
#pragma unroll
      for (int n = 0; n < 4; n++) {
        int row = wc * 64 + n * 16 + l15;
        int xx = (kk * 4 + lgrp) ^ (row & 7);
        b[n] = __builtin_bit_cast(bf16x8, *(const u16x8*)&Bs[row * 64 + xx * 8]);
      }
#pragma unroll
      for (int m = 0; m < 4; m++)
#pragma unroll
        for (int n = 0; n < 4; n++)
          acc[m][n] = __builtin_amdgcn_mfma_f32_16x16x32_bf16(a[m], b[n], acc[m][n], 0, 0, 0);
    }
  }
  if (WM == 2 && n0 >= 1024) {
    // V-tile: transpose 128x128 via LDS (2 passes of 64 cols), write Vt coalesced.
    __syncthreads();
#pragma unroll
    for (int p = 0; p < 2; p++) {
      if (wc == p) {
#pragma unroll
        for (int m = 0; m < 4; m++)
#pragma unroll
          for (int n = 0; n < 4; n++)
#pragma unroll
            for (int r = 0; r < 4; r++)
              sm.T[n * 16 + l15][wr * 64 + m * 16 + lgrp * 4 + r] = bf16bits(acc[m][n][r]);
      }
      __syncthreads();
      int c = tid >> 2, rcb = tid & 3;
#pragma unroll
      for (int it = 0; it < 4; it++) {
        int rc = it * 4 + rcb;
        *(u16x8*)&Vt[(size_t)(n0 - 1024 + p * 64 + c) * 8192 + m0 + rc * 8] =
            *(const u16x8*)&sm.T[c][rc * 8];
      }
      if (p == 0) __syncthreads();
    }
    return;
  }
#pragma unroll
  for (int m = 0; m < 4; m++) {
#pragma unroll
    for (int n = 0; n < 4; n++) {
      int gcol = n0 + wc * 64 + n * 16 + l15;
#pragma unroll
      for (int r = 0; r < 4; r++) {
        int grow = m0 + wr * 64 + m * 16 + lgrp * 4 + r;
        float v = acc[m][n][r];
        if (WM == 1) {
          if (RES) v += Cf[(size_t)grow * 512 + gcol];
          Cf[(size_t)grow * 512 + gcol] = v;
          Cb[(size_t)grow * 512 + gcol] = bf16bits(v);
        } else {
          Cb[(size_t)grow * 1024 + gcol] = bf16bits(v);
        }
      }
    }
  }
}

// ---- MFMA flash attention (round-8 structure): one WG (4 waves) per (block, head) ----
// g-loop over 2 q-groups of 32; single K/V staging per WG; grid 256.
__global__ void __launch_bounds__(256)
k_attn_mfma(const unsigned short* __restrict__ QKb, const unsigned short* __restrict__ Vt,
            unsigned short* __restrict__ O16) {
  __shared__ __align__(16) unsigned short Ks[256 * 64];  // [key][d] swz ^(key&7)
  __shared__ __align__(16) unsigned short Vs[64 * 256];  // [dv][key] swz ^(dv&7)
  int bid = blockIdx.x >> 3, head = blockIdx.x & 7;
  int r0 = bid * 256;
  int tid = threadIdx.x, lane = tid & 63, wid = tid >> 6;
  {
    int key = tid >> 3, j = tid & 7;
#pragma unroll
    for (int p = 0; p < 8; p++) {
      int k2 = key + p * 32;
      u16x8 v = *(const u16x8*)&QKb[(size_t)(r0 + k2) * 1024 + 512 + head * 64 + j * 8];
      *(u16x8*)&Ks[k2 * 64 + ((j ^ (k2 & 7)) * 8)] = v;
    }
    int dv = tid >> 2, sg = tid & 3;
    const unsigned short* src = &Vt[(size_t)(head * 64 + dv) * 8192 + r0 + sg * 64];
#pragma unroll
    for (int c = 0; c < 8; c++) {
      u16x8 v = *(const u16x8*)&src[c * 8];
      int ch = sg * 8 + c;
      *(u16x8*)&Vs[dv * 256 + ((ch ^ (dv & 7)) * 8)] = v;
    }
  }
  int l31 = lane & 31, hi = lane >> 5;
  int qb = wid * 64;
  bf16x8 qfrag[2][4];
#pragma unroll
  for (int g = 0; g < 2; g++)
#pragma unroll
    for (int s = 0; s < 4; s++)
      qfrag[g][s] = __builtin_bit_cast(
          bf16x8, *(const u16x8*)&QKb[(size_t)(r0 + qb + g * 32 + l31) * 1024 + head * 64 +
                                      s * 16 + hi * 8]);
  __syncthreads();

  f32x16 oacc[2][2] = {};
  float mx[2] = {-1e30f, -1e30f}, lsum[2] = {0.f, 0.f};

  for (int kt = 0; kt < 8; kt++) {
    bf16x8 kfrag[4];
    int key = kt * 32 + l31;
#pragma unroll
    for (int s = 0; s < 4; s++) {
      int j = s * 2 + hi;
      kfrag[s] = __builtin_bit_cast(bf16x8, *(const u16x8*)&Ks[key * 64 + ((j ^ (key & 7)) * 8)]);
    }
#pragma unroll
    for (int g = 0; g < 2; g++) {
      f32x16 sacc = {};
#pragma unroll
      for (int s = 0; s < 4; s++)
        sacc = __builtin_amdgcn_mfma_f32_32x32x16_bf16(kfrag[s], qfrag[g][s], sacc, 0, 0, 0);
      float tmax = sacc[0];
#pragma unroll
      for (int r = 1; r < 16; r++) tmax = fmaxf(tmax, sacc[r]);
      tmax = fmaxf(tmax, __shfl_xor(tmax, 32, 64));
      float mn = fmaxf(mx[g], tmax);
      float sc = __expf((mx[g] - mn) * 0.125f);
      float p[16], ts = 0.f;
#pragma unroll
      for (int r = 0; r < 16; r++) {
        p[r] = __expf((sacc[r] - mn) * 0.125f);
        ts += p[r];
      }
      ts += __shfl_xor(ts, 32, 64);
      lsum[g] = lsum[g] * sc + ts;
      mx[g] = mn;
#pragma unroll
      for (int dvt = 0; dvt < 2; dvt++)
#pragma unroll
        for (int r = 0; r < 16; r++) oacc[g][dvt][r] *= sc;
#pragma unroll
      for (int st = 0; st < 2; st++) {
        unsigned int Aw = pk2(p[st * 8 + 0], p[st * 8 + 1]);
        unsigned int Bw = pk2(p[st * 8 + 2], p[st * 8 + 3]);
        unsigned int Cw = pk2(p[st * 8 + 4], p[st * 8 + 5]);
        unsigned int Dw = pk2(p[st * 8 + 6], p[st * 8 + 7]);
        asm volatile("v_permlane32_swap_b32 %0, %1" : "+v"(Aw), "+v"(Cw));
        asm volatile("v_permlane32_swap_b32 %0, %1" : "+v"(Bw), "+v"(Dw));
        u32x4 fw = {Aw, Bw, Cw, Dw};
        bf16x8 pfrag = __builtin_bit_cast(bf16x8, fw);
#pragma unroll
        for (int dvt = 0; dvt < 2; dvt++) {
          int dv = dvt * 32 + l31;
          int ch = kt * 4 + st * 2 + hi;
          bf16x8 vfrag = __builtin_bit_cast(
              bf16x8, *(const u16x8*)&Vs[dv * 256 + ((ch ^ (dv & 7)) * 8)]);
          oacc[g][dvt] = __builtin_amdgcn_mfma_f32_32x32x16_bf16(vfrag, pfrag, oacc[g][dvt], 0, 0, 0);
        }
      }
    }
  }
#pragma unroll
  for (int g = 0; g < 2; g++) {
    float inv = 1.f / lsum[g];
    size_t rowb = (size_t)(r0 + qb + g * 32 + l31) * 512 + head * 64;
#pragma unroll
    for (int dvt = 0; dvt < 2; dvt++)
#pragma unroll
      for (int r = 0; r < 16; r += 2) {
        int dv = dvt * 32 + (r & 3) + 8 * (r >> 2) + 4 * hi;
        unsigned int po = pk2(oacc[g][dvt][r] * inv, oacc[g][dvt][r + 1] * inv);
        *(unsigned int*)&O16[rowb + dv] = po;
      }
  }
}

// ------- writeout: LDS transpose; coalesced H reads, full-line out writes -------
__global__ void k_writeout(const float* __restrict__ H, float* __restrict__ out) {
  __shared__ float t[512][33];
  int bp = blockIdx.x;
  int d0 = blockIdx.y * 32;
  int tid = threadIdx.x;
  int base_row = bp * 512;
#pragma unroll
  for (int i = 0; i < 16; i++) {
    int id = i * 256 + tid;
    int r = id >> 3, c = id & 7;
    float4 v = *(const float4*)&H[(size_t)(base_row + r) * 512 + d0 + c * 4];
    t[r][c * 4 + 0] = v.x;
    t[r][c * 4 + 1] = v.y;
    t[r][c * 4 + 2] = v.z;
    t[r][c * 4 + 3] = v.w;
  }
  __syncthreads();
  int b = bp >> 2, bt = (bp >> 1) & 1, bh = bp & 1;
  int w = tid & 15, lh = (tid >> 4) & 7, ltl = tid >> 7;
  int lw = w & 7, bw = w >> 3;
#pragma unroll
  for (int dd = 0; dd < 32; dd++) {
#pragma unroll
    for (int s = 0; s < 2; s++) {
      int lt = s * 2 + ltl;
      int pos = bw * 256 + lt * 64 + lh * 8 + lw;
      out[((size_t)(b * 512 + d0 + dd) * 8 + bt * 4 + lt) * 256 + (bh * 8 + lh) * 16 + w] =
          t[pos][dd];
    }
  }
}

extern "C" void kernel_launch(void* const* d_in, const int* in_sizes, int n_in,
                              void* d_out, int out_size, void* d_ws, size_t ws_size,
                              hipStream_t stream) {
  const int* x = (const int*)d_in[0];
  const int* slice_idx = (const int*)d_in[1];
  const float* conv_w = (const float*)d_in[2];
  const float* conv_b = (const float*)d_in[3];
  const float* slice_emb = (const float*)d_in[4];
  const float* proj_w = (const float*)d_in[5];
  const float* wq = (const float*)d_in[6];
  const float* wk = (const float*)d_in[7];
  const float* wv = (const float*)d_in[8];
  const float* wo = (const float*)d_in[9];
  float* out = (float*)d_out;

  float* ws = (float*)d_ws;
  unsigned short* wTb = (unsigned short*)ws;                // 8192x512 bf16, 8 MiB
  float* H = ws + 4194304;                                  // f32 trunk 16 MiB
  unsigned short* H0b = (unsigned short*)(ws + 8388608);    // 8 MiB
  unsigned short* Hb = (unsigned short*)(ws + 10485760);    // 8 MiB
  unsigned short* Ob16 = (unsigned short*)(ws + 12582912);  // 8 MiB
  unsigned short* QKb = (unsigned short*)(ws + 14680064);   // 8192x1024 bf16, 16 MiB
  unsigned short* Vt = (unsigned short*)(ws + 18874368);    // 512x8192 bf16, 8 MiB
  unsigned short* Wb = (unsigned short*)(ws + 20971520);    // 9 x 512x512 bf16, 4.5 MiB

  k_prep<<<1600, 256, 0, stream>>>(conv_w, proj_w, wq, wk, wv, wo, wTb, Wb);
  k_embed<<<2048, 256, 0, stream>>>(x, slice_idx, wTb, conv_b, slice_emb, H0b);
  k_gemm_mfma<1, false><<<dim3(64, 4), 256, 0, stream>>>(H0b, Wb, H, Hb, nullptr);

  for (int L = 0; L < 2; L++) {
    k_gemm_mfma<2, false><<<dim3(64, 12), 256, 0, stream>>>(
        Hb, Wb + (size_t)262144 * (1 + 4 * L), nullptr, QKb, Vt);
    k_attn_mfma<<<256, 256, 0, stream>>>(QKb, Vt, Ob16);
    k_gemm_mfma<1, true><<<dim3(64, 4), 256, 0, stream>>>(
        Ob16, Wb + (size_t)262144 * (4 + 4 * L), H, Hb, nullptr);
  }
  k_writeout<<<dim3(16, 16), 256, 0, stream>>>(H, out);
}